// Round 1
// baseline (680.864 us; speedup 1.0000x reference)
//
#include <hip/hip_runtime.h>

// 2-layer GCN (PyG GCNConv): self-loops, symmetric deg-norm, bias.
// Pipeline: detect idx dtype -> deg -> scan -> CSR scatter ->
//           s1=(x@W1)*dis -> agg1(+b1,relu) -> s2=(h@W2)*dis -> agg2(+b2)

__global__ void k_detect(const unsigned* __restrict__ ei, int* __restrict__ flag) {
  if (threadIdx.x == 0 && blockIdx.x == 0) {
    int is64 = 1;
    for (int i = 1; i < 256; i += 2)
      if (ei[i] != 0u) { is64 = 0; break; }
    *flag = is64;
  }
}

__global__ void k_deg_init(int* __restrict__ deg, int n) {
  int i = blockIdx.x * blockDim.x + threadIdx.x;
  if (i < n) deg[i] = 1;   // self-loop
}

__device__ __forceinline__ int ld_idx(const void* ei, int is64, long long i) {
  return is64 ? (int)((const long long*)ei)[i] : ((const int*)ei)[i];
}

__global__ void k_deg_count(const void* __restrict__ ei, const int* __restrict__ flag,
                            int* __restrict__ deg, int e) {
  int i = blockIdx.x * blockDim.x + threadIdx.x;
  if (i >= e) return;
  int is64 = *flag;
  int d = ld_idx(ei, is64, (long long)e + i);  // dst row
  atomicAdd(&deg[d], 1);
}

// single-block exclusive scan of (deg[i]-1) -> rowptr, rowptr[n]=E
__global__ __launch_bounds__(1024) void k_scan(const int* __restrict__ deg,
                                               int* __restrict__ rowptr, int n) {
  __shared__ int sums[1024];
  int tid = threadIdx.x;
  int seg = (n + 1023) >> 10;
  int start = tid * seg;
  int end = start + seg; if (end > n) end = n;
  int s = 0;
  for (int i = start; i < end; ++i) s += deg[i] - 1;
  sums[tid] = s;
  __syncthreads();
  for (int off = 1; off < 1024; off <<= 1) {
    int v = (tid >= off) ? sums[tid - off] : 0;
    __syncthreads();
    sums[tid] += v;
    __syncthreads();
  }
  int run = (tid == 0) ? 0 : sums[tid - 1];
  for (int i = start; i < end; ++i) { rowptr[i] = run; run += deg[i] - 1; }
  if (tid == 1023) rowptr[n] = run;
}

__global__ void k_fill(const int* __restrict__ deg, const int* __restrict__ rowptr,
                       float* __restrict__ dis, int* __restrict__ cursor, int n) {
  int i = blockIdx.x * blockDim.x + threadIdx.x;
  if (i < n) { dis[i] = rsqrtf((float)deg[i]); cursor[i] = rowptr[i]; }
}

__global__ void k_scatter(const void* __restrict__ ei, const int* __restrict__ flag,
                          int* __restrict__ cursor, int* __restrict__ csr, int e) {
  int i = blockIdx.x * blockDim.x + threadIdx.x;
  if (i >= e) return;
  int is64 = *flag;
  int s = ld_idx(ei, is64, i);                  // src row
  int d = ld_idx(ei, is64, (long long)e + i);   // dst row
  int p = atomicAdd(&cursor[d], 1);
  csr[p] = s;
}

__device__ __forceinline__ void fma4(float4& a, float s, const float4& w) {
  a.x = fmaf(s, w.x, a.x); a.y = fmaf(s, w.y, a.y);
  a.z = fmaf(s, w.z, a.z); a.w = fmaf(s, w.w, a.w);
}

// S[r][c] = dis[r] * sum_k X[r][k]*W[k][c].  K=128 fixed.
template <int NCOL>
__global__ __launch_bounds__(256) void k_gemm(const float* __restrict__ X,
                                              const float* __restrict__ W,
                                              const float* __restrict__ dis,
                                              float* __restrict__ S, int nrows) {
  constexpr int CQ = NCOL / 4;      // col-quads: 32 (128) or 16 (64)
  constexpr int ROWS = 4096 / NCOL; // rows per pass: 32 or 64
  __shared__ __align__(16) float Wl[128 * NCOL];
  __shared__ __align__(16) float xs[ROWS * 128];
  float4* Wl4 = (float4*)Wl;
  float4* xs4 = (float4*)xs;
  int tid = threadIdx.x;
  for (int i = tid; i < 128 * NCOL / 4; i += 256)
    Wl4[i] = ((const float4*)W)[i];
  int cq = tid % CQ;
  int rg = tid / CQ;
  int rb = rg * 4;
  int npass = (nrows + ROWS - 1) / ROWS;
  for (int p = blockIdx.x; p < npass; p += gridDim.x) {
    int r0 = p * ROWS;
    __syncthreads();  // xs reuse + (first pass) Wl ready ordering below
    for (int i = tid; i < ROWS * 32; i += 256) {
      int rr = i >> 5, c4 = i & 31;
      int gr = r0 + rr;
      float4 v = make_float4(0.f, 0.f, 0.f, 0.f);
      if (gr < nrows) v = ((const float4*)X)[(size_t)gr * 32 + c4];
      xs4[i] = v;
    }
    __syncthreads();
    float4 acc[4];
#pragma unroll
    for (int i = 0; i < 4; ++i) acc[i] = make_float4(0.f, 0.f, 0.f, 0.f);
#pragma unroll 4
    for (int k4 = 0; k4 < 32; ++k4) {
      float4 xv0 = xs4[(rb + 0) * 32 + k4];
      float4 xv1 = xs4[(rb + 1) * 32 + k4];
      float4 xv2 = xs4[(rb + 2) * 32 + k4];
      float4 xv3 = xs4[(rb + 3) * 32 + k4];
      float4 w0 = Wl4[(k4 * 4 + 0) * CQ + cq];
      float4 w1 = Wl4[(k4 * 4 + 1) * CQ + cq];
      float4 w2 = Wl4[(k4 * 4 + 2) * CQ + cq];
      float4 w3 = Wl4[(k4 * 4 + 3) * CQ + cq];
      fma4(acc[0], xv0.x, w0); fma4(acc[0], xv0.y, w1); fma4(acc[0], xv0.z, w2); fma4(acc[0], xv0.w, w3);
      fma4(acc[1], xv1.x, w0); fma4(acc[1], xv1.y, w1); fma4(acc[1], xv1.z, w2); fma4(acc[1], xv1.w, w3);
      fma4(acc[2], xv2.x, w0); fma4(acc[2], xv2.y, w1); fma4(acc[2], xv2.z, w2); fma4(acc[2], xv2.w, w3);
      fma4(acc[3], xv3.x, w0); fma4(acc[3], xv3.y, w1); fma4(acc[3], xv3.z, w2); fma4(acc[3], xv3.w, w3);
    }
#pragma unroll
    for (int i = 0; i < 4; ++i) {
      int gr = r0 + rb + i;
      if (gr < nrows) {
        float d = dis[gr];
        float4 o = make_float4(acc[i].x * d, acc[i].y * d, acc[i].z * d, acc[i].w * d);
        ((float4*)S)[(size_t)gr * CQ + cq] = o;
      }
    }
  }
}

// h[i] = relu(dis[i]*(s[i] + sum_{j in nbr(i)} s[j]) + b), 128 cols, float2/lane
__global__ __launch_bounds__(256) void k_agg1(const float* __restrict__ S,
                                              const int* __restrict__ rowptr,
                                              const int* __restrict__ csr,
                                              const float* __restrict__ dis,
                                              const float* __restrict__ b,
                                              float* __restrict__ H, int n) {
  int node = blockIdx.x * 4 + (threadIdx.x >> 6);
  if (node >= n) return;
  int lane = threadIdx.x & 63;
  const float2* S2 = (const float2*)S;
  float2 acc = S2[(size_t)node * 64 + lane];  // self-loop term
  int lo = rowptr[node], hi = rowptr[node + 1];
  int e = lo;
  for (; e + 1 < hi; e += 2) {
    int j0 = csr[e], j1 = csr[e + 1];
    float2 v0 = S2[(size_t)j0 * 64 + lane];
    float2 v1 = S2[(size_t)j1 * 64 + lane];
    acc.x += v0.x + v1.x;
    acc.y += v0.y + v1.y;
  }
  if (e < hi) {
    float2 v = S2[(size_t)csr[e] * 64 + lane];
    acc.x += v.x; acc.y += v.y;
  }
  float d = dis[node];
  float2 bb = ((const float2*)b)[lane];
  float hx = fmaf(acc.x, d, bb.x);
  float hy = fmaf(acc.y, d, bb.y);
  ((float2*)H)[(size_t)node * 64 + lane] = make_float2(fmaxf(hx, 0.f), fmaxf(hy, 0.f));
}

// out[i] = dis[i]*(s[i] + sum nbr s[j]) + b, 64 cols, scalar/lane
__global__ __launch_bounds__(256) void k_agg2(const float* __restrict__ S,
                                              const int* __restrict__ rowptr,
                                              const int* __restrict__ csr,
                                              const float* __restrict__ dis,
                                              const float* __restrict__ b,
                                              float* __restrict__ O, int n) {
  int node = blockIdx.x * 4 + (threadIdx.x >> 6);
  if (node >= n) return;
  int lane = threadIdx.x & 63;
  float acc = S[(size_t)node * 64 + lane];
  int lo = rowptr[node], hi = rowptr[node + 1];
  int e = lo;
  for (; e + 1 < hi; e += 2) {
    int j0 = csr[e], j1 = csr[e + 1];
    acc += S[(size_t)j0 * 64 + lane] + S[(size_t)j1 * 64 + lane];
  }
  if (e < hi) acc += S[(size_t)csr[e] * 64 + lane];
  O[(size_t)node * 64 + lane] = fmaf(acc, dis[node], b[lane]);
}

extern "C" void kernel_launch(void* const* d_in, const int* in_sizes, int n_in,
                              void* d_out, int out_size, void* d_ws, size_t ws_size,
                              hipStream_t stream) {
  const float* x  = (const float*)d_in[0];
  const void*  ei = d_in[1];
  const float* W1 = (const float*)d_in[2];
  const float* b1 = (const float*)d_in[3];
  const float* W2 = (const float*)d_in[4];
  const float* b2 = (const float*)d_in[5];
  float* out = (float*)d_out;

  const int N = in_sizes[0] / 128;   // 100000
  const int E = in_sizes[1] / 2;     // 1600000

  char* w = (char*)d_ws;
  size_t off = 0;
  auto alloc = [&](size_t bytes) -> void* {
    void* p = (void*)(w + off);
    off += (bytes + 255) & ~(size_t)255;
    return p;
  };
  int*   deg    = (int*)alloc((size_t)N * 4);
  int*   rowptr = (int*)alloc((size_t)(N + 1) * 4);
  int*   cursor = (int*)alloc((size_t)N * 4);
  float* dis    = (float*)alloc((size_t)N * 4);
  int*   csr    = (int*)alloc((size_t)E * 4);
  float* s      = (float*)alloc((size_t)N * 128 * 4);  // s1, then s2
  float* h      = (float*)alloc((size_t)N * 128 * 4);
  int*   flag   = (int*)alloc(4);

  int gN = (N + 255) / 256;
  int gE = (E + 255) / 256;

  k_detect<<<1, 64, 0, stream>>>((const unsigned*)ei, flag);
  k_deg_init<<<gN, 256, 0, stream>>>(deg, N);
  k_deg_count<<<gE, 256, 0, stream>>>(ei, flag, deg, E);
  k_scan<<<1, 1024, 0, stream>>>(deg, rowptr, N);
  k_fill<<<gN, 256, 0, stream>>>(deg, rowptr, dis, cursor, N);
  k_scatter<<<gE, 256, 0, stream>>>(ei, flag, cursor, csr, E);

  k_gemm<128><<<1024, 256, 0, stream>>>(x, W1, dis, s, N);
  k_agg1<<<(N + 3) / 4, 256, 0, stream>>>(s, rowptr, csr, dis, b1, h, N);
  k_gemm<64><<<1024, 256, 0, stream>>>(h, W2, dis, s, N);
  k_agg2<<<(N + 3) / 4, 256, 0, stream>>>(s, rowptr, csr, dis, b2, out, N);
}

// Round 2
// 541.290 us; speedup vs baseline: 1.2579x; 1.2579x over previous
//
#include <hip/hip_runtime.h>

// 2-layer GCN (PyG GCNConv): self-loops, symmetric deg-norm, bias.
// Pipeline: detect idx dtype -> deg -> hierarchical scan (+dis/cursor) ->
//           CSR scatter -> s1=(x@W1)*dis -> agg1(+b1,relu) -> s2=(h@W2)*dis -> agg2(+b2)

constexpr int SCAN_CHUNK = 4096;  // per block: 256 threads x 16 elems

__global__ void k_detect(const unsigned* __restrict__ ei, int* __restrict__ flag) {
  if (threadIdx.x == 0 && blockIdx.x == 0) {
    int is64 = 1;
    for (int i = 1; i < 256; i += 2)
      if (ei[i] != 0u) { is64 = 0; break; }
    *flag = is64;
  }
}

__global__ void k_deg_init(int* __restrict__ deg, int n) {
  int i = blockIdx.x * blockDim.x + threadIdx.x;
  if (i < n) deg[i] = 1;   // self-loop
}

__device__ __forceinline__ int ld_idx(const void* ei, int is64, long long i) {
  return is64 ? (int)((const long long*)ei)[i] : ((const int*)ei)[i];
}

__global__ void k_deg_count(const void* __restrict__ ei, const int* __restrict__ flag,
                            int* __restrict__ deg, int e) {
  int i = blockIdx.x * blockDim.x + threadIdx.x;
  if (i >= e) return;
  int is64 = *flag;
  int d = ld_idx(ei, is64, (long long)e + i);  // dst row
  atomicAdd(&deg[d], 1);
}

// ---- hierarchical exclusive scan of (deg[i]-1) -> rowptr/cursor, dis = rsqrt(deg) ----

__global__ __launch_bounds__(256) void k_scan_part(const int* __restrict__ deg,
                                                   int* __restrict__ partial, int n) {
  __shared__ int red[256];
  int b = blockIdx.x, tid = threadIdx.x;
  int base = b * SCAN_CHUNK + tid * 16;
  int s = 0;
#pragma unroll
  for (int i = 0; i < 16; ++i) {
    int idx = base + i;
    if (idx < n) s += deg[idx] - 1;
  }
  red[tid] = s;
  __syncthreads();
  for (int off = 128; off > 0; off >>= 1) {
    if (tid < off) red[tid] += red[tid + off];
    __syncthreads();
  }
  if (tid == 0) partial[b] = red[0];
}

// nparts <= 256
__global__ __launch_bounds__(256) void k_scan_top(int* __restrict__ partial, int nparts) {
  __shared__ int sums[256];
  int tid = threadIdx.x;
  sums[tid] = (tid < nparts) ? partial[tid] : 0;
  __syncthreads();
  for (int off = 1; off < 256; off <<= 1) {
    int t = (tid >= off) ? sums[tid - off] : 0;
    __syncthreads();
    sums[tid] += t;
    __syncthreads();
  }
  if (tid < nparts) partial[tid] = (tid == 0) ? 0 : sums[tid - 1];  // exclusive
}

__global__ __launch_bounds__(256) void k_scan_write(const int* __restrict__ deg,
                                                    const int* __restrict__ partial,
                                                    int* __restrict__ rowptr,
                                                    int* __restrict__ cursor,
                                                    float* __restrict__ dis,
                                                    int n, int e) {
  __shared__ int tsum[256];
  int b = blockIdx.x, tid = threadIdx.x;
  int base = b * SCAN_CHUNK + tid * 16;
  int vals[16];
  int dg[16];
  int s = 0;
#pragma unroll
  for (int i = 0; i < 16; ++i) {
    int idx = base + i;
    dg[i] = (idx < n) ? deg[idx] : 1;
    vals[i] = s;
    s += dg[i] - 1;
  }
  tsum[tid] = s;
  __syncthreads();
  for (int off = 1; off < 256; off <<= 1) {
    int t = (tid >= off) ? tsum[tid - off] : 0;
    __syncthreads();
    tsum[tid] += t;
    __syncthreads();
  }
  int toff = partial[b] + ((tid == 0) ? 0 : tsum[tid - 1]);
#pragma unroll
  for (int i = 0; i < 16; ++i) {
    int idx = base + i;
    if (idx < n) {
      int rp = toff + vals[i];
      rowptr[idx] = rp;
      cursor[idx] = rp;
      dis[idx] = rsqrtf((float)dg[i]);
    }
  }
  if (b == 0 && tid == 0) rowptr[n] = e;
}

__global__ void k_scatter(const void* __restrict__ ei, const int* __restrict__ flag,
                          int* __restrict__ cursor, int* __restrict__ csr, int e) {
  int i = blockIdx.x * blockDim.x + threadIdx.x;
  if (i >= e) return;
  int is64 = *flag;
  int s = ld_idx(ei, is64, i);                  // src row
  int d = ld_idx(ei, is64, (long long)e + i);   // dst row
  int p = atomicAdd(&cursor[d], 1);
  csr[p] = s;
}

__device__ __forceinline__ void fma4(float4& a, float s, const float4& w) {
  a.x = fmaf(s, w.x, a.x); a.y = fmaf(s, w.y, a.y);
  a.z = fmaf(s, w.z, a.z); a.w = fmaf(s, w.w, a.w);
}

// S[r][c] = dis[r] * sum_k X[r][k]*W[k][c].  K=128 fixed.
template <int NCOL>
__global__ __launch_bounds__(256) void k_gemm(const float* __restrict__ X,
                                              const float* __restrict__ W,
                                              const float* __restrict__ dis,
                                              float* __restrict__ S, int nrows) {
  constexpr int CQ = NCOL / 4;      // col-quads: 32 (128) or 16 (64)
  constexpr int ROWS = 4096 / NCOL; // rows per pass: 32 or 64
  __shared__ __align__(16) float Wl[128 * NCOL];
  __shared__ __align__(16) float xs[ROWS * 128];
  float4* Wl4 = (float4*)Wl;
  float4* xs4 = (float4*)xs;
  int tid = threadIdx.x;
  for (int i = tid; i < 128 * NCOL / 4; i += 256)
    Wl4[i] = ((const float4*)W)[i];
  int cq = tid % CQ;
  int rg = tid / CQ;
  int rb = rg * 4;
  int npass = (nrows + ROWS - 1) / ROWS;
  for (int p = blockIdx.x; p < npass; p += gridDim.x) {
    int r0 = p * ROWS;
    __syncthreads();  // xs reuse + (first pass) Wl ready
    for (int i = tid; i < ROWS * 32; i += 256) {
      int rr = i >> 5, c4 = i & 31;
      int gr = r0 + rr;
      float4 v = make_float4(0.f, 0.f, 0.f, 0.f);
      if (gr < nrows) v = ((const float4*)X)[(size_t)gr * 32 + c4];
      xs4[i] = v;
    }
    __syncthreads();
    float4 acc[4];
#pragma unroll
    for (int i = 0; i < 4; ++i) acc[i] = make_float4(0.f, 0.f, 0.f, 0.f);
#pragma unroll 4
    for (int k4 = 0; k4 < 32; ++k4) {
      float4 xv0 = xs4[(rb + 0) * 32 + k4];
      float4 xv1 = xs4[(rb + 1) * 32 + k4];
      float4 xv2 = xs4[(rb + 2) * 32 + k4];
      float4 xv3 = xs4[(rb + 3) * 32 + k4];
      float4 w0 = Wl4[(k4 * 4 + 0) * CQ + cq];
      float4 w1 = Wl4[(k4 * 4 + 1) * CQ + cq];
      float4 w2 = Wl4[(k4 * 4 + 2) * CQ + cq];
      float4 w3 = Wl4[(k4 * 4 + 3) * CQ + cq];
      fma4(acc[0], xv0.x, w0); fma4(acc[0], xv0.y, w1); fma4(acc[0], xv0.z, w2); fma4(acc[0], xv0.w, w3);
      fma4(acc[1], xv1.x, w0); fma4(acc[1], xv1.y, w1); fma4(acc[1], xv1.z, w2); fma4(acc[1], xv1.w, w3);
      fma4(acc[2], xv2.x, w0); fma4(acc[2], xv2.y, w1); fma4(acc[2], xv2.z, w2); fma4(acc[2], xv2.w, w3);
      fma4(acc[3], xv3.x, w0); fma4(acc[3], xv3.y, w1); fma4(acc[3], xv3.z, w2); fma4(acc[3], xv3.w, w3);
    }
#pragma unroll
    for (int i = 0; i < 4; ++i) {
      int gr = r0 + rb + i;
      if (gr < nrows) {
        float d = dis[gr];
        float4 o = make_float4(acc[i].x * d, acc[i].y * d, acc[i].z * d, acc[i].w * d);
        ((float4*)S)[(size_t)gr * CQ + cq] = o;
      }
    }
  }
}

// h[i] = relu(dis[i]*(s[i] + sum_{j in nbr(i)} s[j]) + b), 128 cols, float2/lane
__global__ __launch_bounds__(256) void k_agg1(const float* __restrict__ S,
                                              const int* __restrict__ rowptr,
                                              const int* __restrict__ csr,
                                              const float* __restrict__ dis,
                                              const float* __restrict__ b,
                                              float* __restrict__ H, int n) {
  int node = blockIdx.x * 4 + (threadIdx.x >> 6);
  if (node >= n) return;
  int lane = threadIdx.x & 63;
  const float2* S2 = (const float2*)S;
  float2 acc = S2[(size_t)node * 64 + lane];  // self-loop term
  int lo = rowptr[node], hi = rowptr[node + 1];
  int e = lo;
  for (; e + 1 < hi; e += 2) {
    int j0 = csr[e], j1 = csr[e + 1];
    float2 v0 = S2[(size_t)j0 * 64 + lane];
    float2 v1 = S2[(size_t)j1 * 64 + lane];
    acc.x += v0.x + v1.x;
    acc.y += v0.y + v1.y;
  }
  if (e < hi) {
    float2 v = S2[(size_t)csr[e] * 64 + lane];
    acc.x += v.x; acc.y += v.y;
  }
  float d = dis[node];
  float2 bb = ((const float2*)b)[lane];
  float hx = fmaf(acc.x, d, bb.x);
  float hy = fmaf(acc.y, d, bb.y);
  ((float2*)H)[(size_t)node * 64 + lane] = make_float2(fmaxf(hx, 0.f), fmaxf(hy, 0.f));
}

// out[i] = dis[i]*(s[i] + sum nbr s[j]) + b, 64 cols, scalar/lane
__global__ __launch_bounds__(256) void k_agg2(const float* __restrict__ S,
                                              const int* __restrict__ rowptr,
                                              const int* __restrict__ csr,
                                              const float* __restrict__ dis,
                                              const float* __restrict__ b,
                                              float* __restrict__ O, int n) {
  int node = blockIdx.x * 4 + (threadIdx.x >> 6);
  if (node >= n) return;
  int lane = threadIdx.x & 63;
  float acc = S[(size_t)node * 64 + lane];
  int lo = rowptr[node], hi = rowptr[node + 1];
  int e = lo;
  for (; e + 1 < hi; e += 2) {
    int j0 = csr[e], j1 = csr[e + 1];
    acc += S[(size_t)j0 * 64 + lane] + S[(size_t)j1 * 64 + lane];
  }
  if (e < hi) acc += S[(size_t)csr[e] * 64 + lane];
  O[(size_t)node * 64 + lane] = fmaf(acc, dis[node], b[lane]);
}

extern "C" void kernel_launch(void* const* d_in, const int* in_sizes, int n_in,
                              void* d_out, int out_size, void* d_ws, size_t ws_size,
                              hipStream_t stream) {
  const float* x  = (const float*)d_in[0];
  const void*  ei = d_in[1];
  const float* W1 = (const float*)d_in[2];
  const float* b1 = (const float*)d_in[3];
  const float* W2 = (const float*)d_in[4];
  const float* b2 = (const float*)d_in[5];
  float* out = (float*)d_out;

  const int N = in_sizes[0] / 128;   // 100000
  const int E = in_sizes[1] / 2;     // 1600000

  char* w = (char*)d_ws;
  size_t off = 0;
  auto alloc = [&](size_t bytes) -> void* {
    void* p = (void*)(w + off);
    off += (bytes + 255) & ~(size_t)255;
    return p;
  };
  int*   deg     = (int*)alloc((size_t)N * 4);
  int*   rowptr  = (int*)alloc((size_t)(N + 1) * 4);
  int*   cursor  = (int*)alloc((size_t)N * 4);
  float* dis     = (float*)alloc((size_t)N * 4);
  int*   csr     = (int*)alloc((size_t)E * 4);
  float* s       = (float*)alloc((size_t)N * 128 * 4);  // s1, then s2
  float* h       = (float*)alloc((size_t)N * 128 * 4);
  int*   flag    = (int*)alloc(4);
  int*   partial = (int*)alloc(256 * 4);

  int gN = (N + 255) / 256;
  int gE = (E + 255) / 256;
  int nparts = (N + SCAN_CHUNK - 1) / SCAN_CHUNK;  // 25 for N=100K (<=256 required)

  k_detect<<<1, 64, 0, stream>>>((const unsigned*)ei, flag);
  k_deg_init<<<gN, 256, 0, stream>>>(deg, N);
  k_deg_count<<<gE, 256, 0, stream>>>(ei, flag, deg, E);
  k_scan_part<<<nparts, 256, 0, stream>>>(deg, partial, N);
  k_scan_top<<<1, 256, 0, stream>>>(partial, nparts);
  k_scan_write<<<nparts, 256, 0, stream>>>(deg, partial, rowptr, cursor, dis, N, E);
  k_scatter<<<gE, 256, 0, stream>>>(ei, flag, cursor, csr, E);

  k_gemm<128><<<1024, 256, 0, stream>>>(x, W1, dis, s, N);
  k_agg1<<<(N + 3) / 4, 256, 0, stream>>>(s, rowptr, csr, dis, b1, h, N);
  k_gemm<64><<<1024, 256, 0, stream>>>(h, W2, dis, s, N);
  k_agg2<<<(N + 3) / 4, 256, 0, stream>>>(s, rowptr, csr, dis, b2, out, N);
}

// Round 3
// 463.241 us; speedup vs baseline: 1.4698x; 1.1685x over previous
//
#include <hip/hip_runtime.h>

// 2-layer GCN (PyG GCNConv): self-loops, symmetric deg-norm, bias.
// CSR build: deg -> scan -> bucket-histogram partition (coalesced writes) ->
//            per-bucket LDS scatter (coalesced writes).
// Then: s1=(x@W1)*dis -> agg1(+b1,relu) -> s2=(h@W2)*dis -> agg2(+b2)

constexpr int SCAN_CHUNK = 4096;   // per scan block: 256 threads x 16 elems
constexpr int NBKT = 512;          // dst-range buckets
constexpr int EPB  = 8192;         // edges per partition block
constexpr int CSR_CAP = 12288;     // per-bucket LDS CSR capacity (mean ~3130)

__global__ void k_detect(const unsigned* __restrict__ ei, int* __restrict__ flag) {
  if (threadIdx.x == 0 && blockIdx.x == 0) {
    int is64 = 1;
    for (int i = 1; i < 256; i += 2)
      if (ei[i] != 0u) { is64 = 0; break; }
    *flag = is64;
  }
}

__global__ void k_deg_init(int* __restrict__ deg, int n) {
  int i = blockIdx.x * blockDim.x + threadIdx.x;
  if (i < n) deg[i] = 1;   // self-loop
}

__device__ __forceinline__ int ld_idx(const void* ei, int is64, long long i) {
  return is64 ? (int)((const long long*)ei)[i] : ((const int*)ei)[i];
}

__global__ void k_deg_count(const void* __restrict__ ei, const int* __restrict__ flag,
                            int* __restrict__ deg, int e) {
  int i = blockIdx.x * blockDim.x + threadIdx.x;
  if (i >= e) return;
  int is64 = *flag;
  int d = ld_idx(ei, is64, (long long)e + i);  // dst row
  atomicAdd(&deg[d], 1);
}

// ---- hierarchical exclusive scan of (deg[i]-1) -> rowptr/cursor, dis = rsqrt(deg) ----

__global__ __launch_bounds__(256) void k_scan_part(const int* __restrict__ deg,
                                                   int* __restrict__ partial, int n) {
  __shared__ int red[256];
  int b = blockIdx.x, tid = threadIdx.x;
  int base = b * SCAN_CHUNK + tid * 16;
  int s = 0;
#pragma unroll
  for (int i = 0; i < 16; ++i) {
    int idx = base + i;
    if (idx < n) s += deg[idx] - 1;
  }
  red[tid] = s;
  __syncthreads();
  for (int off = 128; off > 0; off >>= 1) {
    if (tid < off) red[tid] += red[tid + off];
    __syncthreads();
  }
  if (tid == 0) partial[b] = red[0];
}

// nparts <= 256; in-place exclusive scan of partials
__global__ __launch_bounds__(256) void k_scan_top(int* __restrict__ partial, int nparts) {
  __shared__ int sums[256];
  int tid = threadIdx.x;
  sums[tid] = (tid < nparts) ? partial[tid] : 0;
  __syncthreads();
  for (int off = 1; off < 256; off <<= 1) {
    int t = (tid >= off) ? sums[tid - off] : 0;
    __syncthreads();
    sums[tid] += t;
    __syncthreads();
  }
  if (tid < nparts) partial[tid] = (tid == 0) ? 0 : sums[tid - 1];  // exclusive
}

__global__ __launch_bounds__(256) void k_scan_write(const int* __restrict__ deg,
                                                    const int* __restrict__ partial,
                                                    int* __restrict__ rowptr,
                                                    int* __restrict__ cursor,
                                                    float* __restrict__ dis,
                                                    int n, int e) {
  __shared__ int tsum[256];
  int b = blockIdx.x, tid = threadIdx.x;
  int base = b * SCAN_CHUNK + tid * 16;
  int vals[16];
  int dg[16];
  int s = 0;
#pragma unroll
  for (int i = 0; i < 16; ++i) {
    int idx = base + i;
    dg[i] = (idx < n) ? deg[idx] : 1;
    vals[i] = s;
    s += dg[i] - 1;
  }
  tsum[tid] = s;
  __syncthreads();
  for (int off = 1; off < 256; off <<= 1) {
    int t = (tid >= off) ? tsum[tid - off] : 0;
    __syncthreads();
    tsum[tid] += t;
    __syncthreads();
  }
  int toff = partial[b] + ((tid == 0) ? 0 : tsum[tid - 1]);
#pragma unroll
  for (int i = 0; i < 16; ++i) {
    int idx = base + i;
    if (idx < n) {
      int rp = toff + vals[i];
      rowptr[idx] = rp;
      cursor[idx] = rp;     // used only by overflow fallback
      dis[idx] = rsqrtf((float)dg[i]);
    }
  }
  if (b == 0 && tid == 0) rowptr[n] = e;
}

// ---- generic hierarchical exclusive scan (for the bucket histogram) ----

__global__ __launch_bounds__(256) void ks_part_g(const int* __restrict__ in,
                                                 int* __restrict__ partial, int m) {
  __shared__ int red[256];
  int b = blockIdx.x, tid = threadIdx.x;
  int base = b * SCAN_CHUNK + tid * 16;
  int s = 0;
#pragma unroll
  for (int i = 0; i < 16; ++i) {
    int idx = base + i;
    if (idx < m) s += in[idx];
  }
  red[tid] = s;
  __syncthreads();
  for (int off = 128; off > 0; off >>= 1) {
    if (tid < off) red[tid] += red[tid + off];
    __syncthreads();
  }
  if (tid == 0) partial[b] = red[0];
}

__global__ __launch_bounds__(256) void ks_write_g(const int* __restrict__ in,
                                                  const int* __restrict__ partial,
                                                  int* __restrict__ out, int m) {
  __shared__ int tsum[256];
  int b = blockIdx.x, tid = threadIdx.x;
  int base = b * SCAN_CHUNK + tid * 16;
  int vals[16];
  int s = 0;
#pragma unroll
  for (int i = 0; i < 16; ++i) {
    int idx = base + i;
    int v = (idx < m) ? in[idx] : 0;
    vals[i] = s;
    s += v;
  }
  tsum[tid] = s;
  __syncthreads();
  for (int off = 1; off < 256; off <<= 1) {
    int t = (tid >= off) ? tsum[tid - off] : 0;
    __syncthreads();
    tsum[tid] += t;
    __syncthreads();
  }
  int toff = partial[b] + ((tid == 0) ? 0 : tsum[tid - 1]);
#pragma unroll
  for (int i = 0; i < 16; ++i) {
    int idx = base + i;
    if (idx < m) out[idx] = toff + vals[i];
  }
}

// ---- bucketed partition: edges -> packed (src | dlocal<<20) grouped by bucket ----

__global__ __launch_bounds__(256) void k_hist(const void* __restrict__ ei,
                                              const int* __restrict__ flag,
                                              int* __restrict__ hist,
                                              int e, int nblk, int npb) {
  __shared__ int h[NBKT];
  int blk = blockIdx.x, tid = threadIdx.x;
  for (int i = tid; i < NBKT; i += 256) h[i] = 0;
  __syncthreads();
  int is64 = *flag;
  int base = blk * EPB;
  int end = base + EPB; if (end > e) end = e;
  for (int i = base + tid; i < end; i += 256) {
    int d = ld_idx(ei, is64, (long long)e + i);
    atomicAdd(&h[d / npb], 1);
  }
  __syncthreads();
  for (int i = tid; i < NBKT; i += 256)
    hist[(size_t)i * nblk + blk] = h[i];   // bucket-major
}

__global__ __launch_bounds__(256) void k_partition(const void* __restrict__ ei,
                                                   const int* __restrict__ flag,
                                                   const int* __restrict__ scanned,
                                                   unsigned* __restrict__ pairbuf,
                                                   int e, int nblk, int npb) {
  __shared__ int off[NBKT];
  int blk = blockIdx.x, tid = threadIdx.x;
  for (int i = tid; i < NBKT; i += 256)
    off[i] = scanned[(size_t)i * nblk + blk];
  __syncthreads();
  int is64 = *flag;
  int base = blk * EPB;
  int end = base + EPB; if (end > e) end = e;
  for (int i = base + tid; i < end; i += 256) {
    int s = ld_idx(ei, is64, i);
    int d = ld_idx(ei, is64, (long long)e + i);
    int bkt = d / npb;
    int pos = atomicAdd(&off[bkt], 1);
    pairbuf[pos] = (unsigned)s | ((unsigned)(d - bkt * npb) << 20);
  }
}

// one block per bucket: LDS-staged exact CSR scatter, coalesced write-out
__global__ __launch_bounds__(256) void k_bucket_csr(const unsigned* __restrict__ pairbuf,
                                                    const int* __restrict__ rowptr,
                                                    int* __restrict__ cursor,
                                                    int* __restrict__ csr,
                                                    int n, int npb) {
  __shared__ int lcsr[CSR_CAP];
  __shared__ int cur[256];       // npb <= 256
  int b = blockIdx.x, tid = threadIdx.x;
  int lo = b * npb;
  if (lo >= n) return;
  int hi = lo + npb; if (hi > n) hi = n;
  int nn = hi - lo;
  int seg_base = rowptr[lo];
  int cnt = rowptr[hi] - seg_base;
  if (cnt <= CSR_CAP) {
    for (int i = tid; i < nn; i += 256) cur[i] = rowptr[lo + i] - seg_base;
    __syncthreads();
    for (int i = tid; i < cnt; i += 256) {
      unsigned p = pairbuf[seg_base + i];
      int q = atomicAdd(&cur[p >> 20], 1);
      lcsr[q] = (int)(p & 0xFFFFFu);
    }
    __syncthreads();
    for (int i = tid; i < cnt; i += 256) csr[seg_base + i] = lcsr[i];
  } else {
    // statistically-unreachable overflow fallback: global atomics
    for (int i = tid; i < cnt; i += 256) {
      unsigned p = pairbuf[seg_base + i];
      int d = lo + (int)(p >> 20);
      int q = atomicAdd(&cursor[d], 1);
      csr[q] = (int)(p & 0xFFFFFu);
    }
  }
}

__device__ __forceinline__ void fma4(float4& a, float s, const float4& w) {
  a.x = fmaf(s, w.x, a.x); a.y = fmaf(s, w.y, a.y);
  a.z = fmaf(s, w.z, a.z); a.w = fmaf(s, w.w, a.w);
}

// S[r][c] = dis[r] * sum_k X[r][k]*W[k][c].  K=128 fixed.
template <int NCOL>
__global__ __launch_bounds__(256) void k_gemm(const float* __restrict__ X,
                                              const float* __restrict__ W,
                                              const float* __restrict__ dis,
                                              float* __restrict__ S, int nrows) {
  constexpr int CQ = NCOL / 4;
  constexpr int ROWS = 4096 / NCOL;
  __shared__ __align__(16) float Wl[128 * NCOL];
  __shared__ __align__(16) float xs[ROWS * 128];
  float4* Wl4 = (float4*)Wl;
  float4* xs4 = (float4*)xs;
  int tid = threadIdx.x;
  for (int i = tid; i < 128 * NCOL / 4; i += 256)
    Wl4[i] = ((const float4*)W)[i];
  int cq = tid % CQ;
  int rg = tid / CQ;
  int rb = rg * 4;
  int npass = (nrows + ROWS - 1) / ROWS;
  for (int p = blockIdx.x; p < npass; p += gridDim.x) {
    int r0 = p * ROWS;
    __syncthreads();
    for (int i = tid; i < ROWS * 32; i += 256) {
      int rr = i >> 5, c4 = i & 31;
      int gr = r0 + rr;
      float4 v = make_float4(0.f, 0.f, 0.f, 0.f);
      if (gr < nrows) v = ((const float4*)X)[(size_t)gr * 32 + c4];
      xs4[i] = v;
    }
    __syncthreads();
    float4 acc[4];
#pragma unroll
    for (int i = 0; i < 4; ++i) acc[i] = make_float4(0.f, 0.f, 0.f, 0.f);
#pragma unroll 4
    for (int k4 = 0; k4 < 32; ++k4) {
      float4 xv0 = xs4[(rb + 0) * 32 + k4];
      float4 xv1 = xs4[(rb + 1) * 32 + k4];
      float4 xv2 = xs4[(rb + 2) * 32 + k4];
      float4 xv3 = xs4[(rb + 3) * 32 + k4];
      float4 w0 = Wl4[(k4 * 4 + 0) * CQ + cq];
      float4 w1 = Wl4[(k4 * 4 + 1) * CQ + cq];
      float4 w2 = Wl4[(k4 * 4 + 2) * CQ + cq];
      float4 w3 = Wl4[(k4 * 4 + 3) * CQ + cq];
      fma4(acc[0], xv0.x, w0); fma4(acc[0], xv0.y, w1); fma4(acc[0], xv0.z, w2); fma4(acc[0], xv0.w, w3);
      fma4(acc[1], xv1.x, w0); fma4(acc[1], xv1.y, w1); fma4(acc[1], xv1.z, w2); fma4(acc[1], xv1.w, w3);
      fma4(acc[2], xv2.x, w0); fma4(acc[2], xv2.y, w1); fma4(acc[2], xv2.z, w2); fma4(acc[2], xv2.w, w3);
      fma4(acc[3], xv3.x, w0); fma4(acc[3], xv3.y, w1); fma4(acc[3], xv3.z, w2); fma4(acc[3], xv3.w, w3);
    }
#pragma unroll
    for (int i = 0; i < 4; ++i) {
      int gr = r0 + rb + i;
      if (gr < nrows) {
        float d = dis[gr];
        float4 o = make_float4(acc[i].x * d, acc[i].y * d, acc[i].z * d, acc[i].w * d);
        ((float4*)S)[(size_t)gr * CQ + cq] = o;
      }
    }
  }
}

// h[i] = relu(dis[i]*(s[i] + sum_{j in nbr(i)} s[j]) + b), 128 cols, float2/lane
__global__ __launch_bounds__(256) void k_agg1(const float* __restrict__ S,
                                              const int* __restrict__ rowptr,
                                              const int* __restrict__ csr,
                                              const float* __restrict__ dis,
                                              const float* __restrict__ b,
                                              float* __restrict__ H, int n) {
  int node = blockIdx.x * 4 + (threadIdx.x >> 6);
  if (node >= n) return;
  int lane = threadIdx.x & 63;
  const float2* S2 = (const float2*)S;
  float2 acc = S2[(size_t)node * 64 + lane];  // self-loop term
  int lo = rowptr[node], hi = rowptr[node + 1];
  int e = lo;
  for (; e + 1 < hi; e += 2) {
    int j0 = csr[e], j1 = csr[e + 1];
    float2 v0 = S2[(size_t)j0 * 64 + lane];
    float2 v1 = S2[(size_t)j1 * 64 + lane];
    acc.x += v0.x + v1.x;
    acc.y += v0.y + v1.y;
  }
  if (e < hi) {
    float2 v = S2[(size_t)csr[e] * 64 + lane];
    acc.x += v.x; acc.y += v.y;
  }
  float d = dis[node];
  float2 bb = ((const float2*)b)[lane];
  float hx = fmaf(acc.x, d, bb.x);
  float hy = fmaf(acc.y, d, bb.y);
  ((float2*)H)[(size_t)node * 64 + lane] = make_float2(fmaxf(hx, 0.f), fmaxf(hy, 0.f));
}

// out[i] = dis[i]*(s[i] + sum nbr s[j]) + b, 64 cols, scalar/lane
__global__ __launch_bounds__(256) void k_agg2(const float* __restrict__ S,
                                              const int* __restrict__ rowptr,
                                              const int* __restrict__ csr,
                                              const float* __restrict__ dis,
                                              const float* __restrict__ b,
                                              float* __restrict__ O, int n) {
  int node = blockIdx.x * 4 + (threadIdx.x >> 6);
  if (node >= n) return;
  int lane = threadIdx.x & 63;
  float acc = S[(size_t)node * 64 + lane];
  int lo = rowptr[node], hi = rowptr[node + 1];
  int e = lo;
  for (; e + 1 < hi; e += 2) {
    int j0 = csr[e], j1 = csr[e + 1];
    acc += S[(size_t)j0 * 64 + lane] + S[(size_t)j1 * 64 + lane];
  }
  if (e < hi) acc += S[(size_t)csr[e] * 64 + lane];
  O[(size_t)node * 64 + lane] = fmaf(acc, dis[node], b[lane]);
}

extern "C" void kernel_launch(void* const* d_in, const int* in_sizes, int n_in,
                              void* d_out, int out_size, void* d_ws, size_t ws_size,
                              hipStream_t stream) {
  const float* x  = (const float*)d_in[0];
  const void*  ei = d_in[1];
  const float* W1 = (const float*)d_in[2];
  const float* b1 = (const float*)d_in[3];
  const float* W2 = (const float*)d_in[4];
  const float* b2 = (const float*)d_in[5];
  float* out = (float*)d_out;

  const int N = in_sizes[0] / 128;   // 100000
  const int E = in_sizes[1] / 2;     // 1600000
  const int npb  = (N + NBKT - 1) / NBKT;    // 196 nodes per bucket
  const int nblk = (E + EPB - 1) / EPB;      // 196 partition blocks
  const int m    = NBKT * nblk;              // histogram entries

  char* w = (char*)d_ws;
  size_t off = 0;
  auto alloc = [&](size_t bytes) -> void* {
    void* p = (void*)(w + off);
    off += (bytes + 255) & ~(size_t)255;
    return p;
  };
  int*      deg     = (int*)alloc((size_t)N * 4);
  int*      rowptr  = (int*)alloc((size_t)(N + 1) * 4);
  int*      cursor  = (int*)alloc((size_t)N * 4);
  float*    dis     = (float*)alloc((size_t)N * 4);
  int*      csr     = (int*)alloc((size_t)E * 4);
  unsigned* pairbuf = (unsigned*)alloc((size_t)E * 4);
  int*      hist    = (int*)alloc((size_t)m * 4);
  int*      scanned = (int*)alloc((size_t)m * 4);
  float*    s       = (float*)alloc((size_t)N * 128 * 4);
  float*    h       = (float*)alloc((size_t)N * 128 * 4);
  int*      flag    = (int*)alloc(4);
  int*      partial = (int*)alloc(256 * 4);

  int gN = (N + 255) / 256;
  int gE = (E + 255) / 256;
  int npartsN = (N + SCAN_CHUNK - 1) / SCAN_CHUNK;  // 25
  int npartsM = (m + SCAN_CHUNK - 1) / SCAN_CHUNK;  // 25

  k_detect<<<1, 64, 0, stream>>>((const unsigned*)ei, flag);
  k_deg_init<<<gN, 256, 0, stream>>>(deg, N);
  k_deg_count<<<gE, 256, 0, stream>>>(ei, flag, deg, E);
  k_scan_part<<<npartsN, 256, 0, stream>>>(deg, partial, N);
  k_scan_top<<<1, 256, 0, stream>>>(partial, npartsN);
  k_scan_write<<<npartsN, 256, 0, stream>>>(deg, partial, rowptr, cursor, dis, N, E);

  k_hist<<<nblk, 256, 0, stream>>>(ei, flag, hist, E, nblk, npb);
  ks_part_g<<<npartsM, 256, 0, stream>>>(hist, partial, m);
  k_scan_top<<<1, 256, 0, stream>>>(partial, npartsM);
  ks_write_g<<<npartsM, 256, 0, stream>>>(hist, partial, scanned, m);
  k_partition<<<nblk, 256, 0, stream>>>(ei, flag, scanned, pairbuf, E, nblk, npb);
  k_bucket_csr<<<NBKT, 256, 0, stream>>>(pairbuf, rowptr, cursor, csr, N, npb);

  k_gemm<128><<<1024, 256, 0, stream>>>(x, W1, dis, s, N);
  k_agg1<<<(N + 3) / 4, 256, 0, stream>>>(s, rowptr, csr, dis, b1, h, N);
  k_gemm<64><<<1024, 256, 0, stream>>>(h, W2, dis, s, N);
  k_agg2<<<(N + 3) / 4, 256, 0, stream>>>(s, rowptr, csr, dis, b2, out, N);
}

// Round 4
// 383.150 us; speedup vs baseline: 1.7770x; 1.2090x over previous
//
#include <hip/hip_runtime.h>

// 2-layer GCN (PyG GCNConv): self-loops, symmetric deg-norm, bias.
// CSR build: deg -> scan -> bucket-histogram partition -> per-bucket LDS scatter.
// Compute: s1=bf16((x@W1)*dis) -> agg1(+b1,relu) -> s2=bf16((h@W2)*dis) -> agg2(+b2)
// S stored bf16 to halve the random-gather L2-fill traffic; fp32 accumulate.

constexpr int SCAN_CHUNK = 4096;   // per scan block: 256 threads x 16 elems
constexpr int NBKT = 512;          // dst-range buckets
constexpr int EPB  = 8192;         // edges per partition block
constexpr int CSR_CAP = 12288;     // per-bucket LDS CSR capacity (mean ~3130)

__device__ __forceinline__ unsigned short f2bf(float f) {
  unsigned u = __float_as_uint(f);
  unsigned r = (u + 0x7FFFu + ((u >> 16) & 1u)) >> 16;   // round-nearest-even
  return (unsigned short)r;
}
__device__ __forceinline__ float bf2f(unsigned short h) {
  return __uint_as_float(((unsigned)h) << 16);
}

__global__ void k_detect(const unsigned* __restrict__ ei, int* __restrict__ flag) {
  if (threadIdx.x == 0 && blockIdx.x == 0) {
    int is64 = 1;
    for (int i = 1; i < 256; i += 2)
      if (ei[i] != 0u) { is64 = 0; break; }
    *flag = is64;
  }
}

__global__ void k_deg_init(int* __restrict__ deg, int n) {
  int i = blockIdx.x * blockDim.x + threadIdx.x;
  if (i < n) deg[i] = 1;   // self-loop
}

__device__ __forceinline__ int ld_idx(const void* ei, int is64, long long i) {
  return is64 ? (int)((const long long*)ei)[i] : ((const int*)ei)[i];
}

__global__ void k_deg_count(const void* __restrict__ ei, const int* __restrict__ flag,
                            int* __restrict__ deg, int e) {
  int i = blockIdx.x * blockDim.x + threadIdx.x;
  if (i >= e) return;
  int is64 = *flag;
  int d = ld_idx(ei, is64, (long long)e + i);  // dst row
  atomicAdd(&deg[d], 1);
}

// ---- hierarchical exclusive scan of (deg[i]-1) -> rowptr/cursor, dis = rsqrt(deg) ----

__global__ __launch_bounds__(256) void k_scan_part(const int* __restrict__ deg,
                                                   int* __restrict__ partial, int n) {
  __shared__ int red[256];
  int b = blockIdx.x, tid = threadIdx.x;
  int base = b * SCAN_CHUNK + tid * 16;
  int s = 0;
#pragma unroll
  for (int i = 0; i < 16; ++i) {
    int idx = base + i;
    if (idx < n) s += deg[idx] - 1;
  }
  red[tid] = s;
  __syncthreads();
  for (int off = 128; off > 0; off >>= 1) {
    if (tid < off) red[tid] += red[tid + off];
    __syncthreads();
  }
  if (tid == 0) partial[b] = red[0];
}

// nparts <= 256; in-place exclusive scan of partials
__global__ __launch_bounds__(256) void k_scan_top(int* __restrict__ partial, int nparts) {
  __shared__ int sums[256];
  int tid = threadIdx.x;
  sums[tid] = (tid < nparts) ? partial[tid] : 0;
  __syncthreads();
  for (int off = 1; off < 256; off <<= 1) {
    int t = (tid >= off) ? sums[tid - off] : 0;
    __syncthreads();
    sums[tid] += t;
    __syncthreads();
  }
  if (tid < nparts) partial[tid] = (tid == 0) ? 0 : sums[tid - 1];  // exclusive
}

__global__ __launch_bounds__(256) void k_scan_write(const int* __restrict__ deg,
                                                    const int* __restrict__ partial,
                                                    int* __restrict__ rowptr,
                                                    int* __restrict__ cursor,
                                                    float* __restrict__ dis,
                                                    int n, int e) {
  __shared__ int tsum[256];
  int b = blockIdx.x, tid = threadIdx.x;
  int base = b * SCAN_CHUNK + tid * 16;
  int vals[16];
  int dg[16];
  int s = 0;
#pragma unroll
  for (int i = 0; i < 16; ++i) {
    int idx = base + i;
    dg[i] = (idx < n) ? deg[idx] : 1;
    vals[i] = s;
    s += dg[i] - 1;
  }
  tsum[tid] = s;
  __syncthreads();
  for (int off = 1; off < 256; off <<= 1) {
    int t = (tid >= off) ? tsum[tid - off] : 0;
    __syncthreads();
    tsum[tid] += t;
    __syncthreads();
  }
  int toff = partial[b] + ((tid == 0) ? 0 : tsum[tid - 1]);
#pragma unroll
  for (int i = 0; i < 16; ++i) {
    int idx = base + i;
    if (idx < n) {
      int rp = toff + vals[i];
      rowptr[idx] = rp;
      cursor[idx] = rp;     // used only by overflow fallback
      dis[idx] = rsqrtf((float)dg[i]);
    }
  }
  if (b == 0 && tid == 0) rowptr[n] = e;
}

// ---- generic hierarchical exclusive scan (for the bucket histogram) ----

__global__ __launch_bounds__(256) void ks_part_g(const int* __restrict__ in,
                                                 int* __restrict__ partial, int m) {
  __shared__ int red[256];
  int b = blockIdx.x, tid = threadIdx.x;
  int base = b * SCAN_CHUNK + tid * 16;
  int s = 0;
#pragma unroll
  for (int i = 0; i < 16; ++i) {
    int idx = base + i;
    if (idx < m) s += in[idx];
  }
  red[tid] = s;
  __syncthreads();
  for (int off = 128; off > 0; off >>= 1) {
    if (tid < off) red[tid] += red[tid + off];
    __syncthreads();
  }
  if (tid == 0) partial[b] = red[0];
}

__global__ __launch_bounds__(256) void ks_write_g(const int* __restrict__ in,
                                                  const int* __restrict__ partial,
                                                  int* __restrict__ out, int m) {
  __shared__ int tsum[256];
  int b = blockIdx.x, tid = threadIdx.x;
  int base = b * SCAN_CHUNK + tid * 16;
  int vals[16];
  int s = 0;
#pragma unroll
  for (int i = 0; i < 16; ++i) {
    int idx = base + i;
    int v = (idx < m) ? in[idx] : 0;
    vals[i] = s;
    s += v;
  }
  tsum[tid] = s;
  __syncthreads();
  for (int off = 1; off < 256; off <<= 1) {
    int t = (tid >= off) ? tsum[tid - off] : 0;
    __syncthreads();
    tsum[tid] += t;
    __syncthreads();
  }
  int toff = partial[b] + ((tid == 0) ? 0 : tsum[tid - 1]);
#pragma unroll
  for (int i = 0; i < 16; ++i) {
    int idx = base + i;
    if (idx < m) out[idx] = toff + vals[i];
  }
}

// ---- bucketed partition: edges -> packed (src | dlocal<<20) grouped by bucket ----

__global__ __launch_bounds__(256) void k_hist(const void* __restrict__ ei,
                                              const int* __restrict__ flag,
                                              int* __restrict__ hist,
                                              int e, int nblk, int npb) {
  __shared__ int h[NBKT];
  int blk = blockIdx.x, tid = threadIdx.x;
  for (int i = tid; i < NBKT; i += 256) h[i] = 0;
  __syncthreads();
  int is64 = *flag;
  int base = blk * EPB;
  int end = base + EPB; if (end > e) end = e;
  for (int i = base + tid; i < end; i += 256) {
    int d = ld_idx(ei, is64, (long long)e + i);
    atomicAdd(&h[d / npb], 1);
  }
  __syncthreads();
  for (int i = tid; i < NBKT; i += 256)
    hist[(size_t)i * nblk + blk] = h[i];   // bucket-major
}

__global__ __launch_bounds__(256) void k_partition(const void* __restrict__ ei,
                                                   const int* __restrict__ flag,
                                                   const int* __restrict__ scanned,
                                                   unsigned* __restrict__ pairbuf,
                                                   int e, int nblk, int npb) {
  __shared__ int off[NBKT];
  int blk = blockIdx.x, tid = threadIdx.x;
  for (int i = tid; i < NBKT; i += 256)
    off[i] = scanned[(size_t)i * nblk + blk];
  __syncthreads();
  int is64 = *flag;
  int base = blk * EPB;
  int end = base + EPB; if (end > e) end = e;
  for (int i = base + tid; i < end; i += 256) {
    int s = ld_idx(ei, is64, i);
    int d = ld_idx(ei, is64, (long long)e + i);
    int bkt = d / npb;
    int pos = atomicAdd(&off[bkt], 1);
    pairbuf[pos] = (unsigned)s | ((unsigned)(d - bkt * npb) << 20);
  }
}

// one block per bucket: LDS-staged exact CSR scatter, coalesced write-out
__global__ __launch_bounds__(256) void k_bucket_csr(const unsigned* __restrict__ pairbuf,
                                                    const int* __restrict__ rowptr,
                                                    int* __restrict__ cursor,
                                                    int* __restrict__ csr,
                                                    int n, int npb) {
  __shared__ int lcsr[CSR_CAP];
  __shared__ int cur[256];       // npb <= 256
  int b = blockIdx.x, tid = threadIdx.x;
  int lo = b * npb;
  if (lo >= n) return;
  int hi = lo + npb; if (hi > n) hi = n;
  int nn = hi - lo;
  int seg_base = rowptr[lo];
  int cnt = rowptr[hi] - seg_base;
  if (cnt <= CSR_CAP) {
    for (int i = tid; i < nn; i += 256) cur[i] = rowptr[lo + i] - seg_base;
    __syncthreads();
    for (int i = tid; i < cnt; i += 256) {
      unsigned p = pairbuf[seg_base + i];
      int q = atomicAdd(&cur[p >> 20], 1);
      lcsr[q] = (int)(p & 0xFFFFFu);
    }
    __syncthreads();
    for (int i = tid; i < cnt; i += 256) csr[seg_base + i] = lcsr[i];
  } else {
    // statistically-unreachable overflow fallback: global atomics
    for (int i = tid; i < cnt; i += 256) {
      unsigned p = pairbuf[seg_base + i];
      int d = lo + (int)(p >> 20);
      int q = atomicAdd(&cursor[d], 1);
      csr[q] = (int)(p & 0xFFFFFu);
    }
  }
}

__device__ __forceinline__ void fma4(float4& a, float s, const float4& w) {
  a.x = fmaf(s, w.x, a.x); a.y = fmaf(s, w.y, a.y);
  a.z = fmaf(s, w.z, a.z); a.w = fmaf(s, w.w, a.w);
}

// S[r][c] = bf16( dis[r] * sum_k X[r][k]*W[k][c] ).  K=128 fixed.
template <int NCOL>
__global__ __launch_bounds__(256) void k_gemm(const float* __restrict__ X,
                                              const float* __restrict__ W,
                                              const float* __restrict__ dis,
                                              unsigned short* __restrict__ S, int nrows) {
  constexpr int CQ = NCOL / 4;
  constexpr int ROWS = 4096 / NCOL;
  __shared__ __align__(16) float Wl[128 * NCOL];
  __shared__ __align__(16) float xs[ROWS * 128];
  float4* Wl4 = (float4*)Wl;
  float4* xs4 = (float4*)xs;
  int tid = threadIdx.x;
  for (int i = tid; i < 128 * NCOL / 4; i += 256)
    Wl4[i] = ((const float4*)W)[i];
  int cq = tid % CQ;
  int rg = tid / CQ;
  int rb = rg * 4;
  int npass = (nrows + ROWS - 1) / ROWS;
  for (int p = blockIdx.x; p < npass; p += gridDim.x) {
    int r0 = p * ROWS;
    __syncthreads();
    for (int i = tid; i < ROWS * 32; i += 256) {
      int rr = i >> 5, c4 = i & 31;
      int gr = r0 + rr;
      float4 v = make_float4(0.f, 0.f, 0.f, 0.f);
      if (gr < nrows) v = ((const float4*)X)[(size_t)gr * 32 + c4];
      xs4[i] = v;
    }
    __syncthreads();
    float4 acc[4];
#pragma unroll
    for (int i = 0; i < 4; ++i) acc[i] = make_float4(0.f, 0.f, 0.f, 0.f);
#pragma unroll 4
    for (int k4 = 0; k4 < 32; ++k4) {
      float4 xv0 = xs4[(rb + 0) * 32 + k4];
      float4 xv1 = xs4[(rb + 1) * 32 + k4];
      float4 xv2 = xs4[(rb + 2) * 32 + k4];
      float4 xv3 = xs4[(rb + 3) * 32 + k4];
      float4 w0 = Wl4[(k4 * 4 + 0) * CQ + cq];
      float4 w1 = Wl4[(k4 * 4 + 1) * CQ + cq];
      float4 w2 = Wl4[(k4 * 4 + 2) * CQ + cq];
      float4 w3 = Wl4[(k4 * 4 + 3) * CQ + cq];
      fma4(acc[0], xv0.x, w0); fma4(acc[0], xv0.y, w1); fma4(acc[0], xv0.z, w2); fma4(acc[0], xv0.w, w3);
      fma4(acc[1], xv1.x, w0); fma4(acc[1], xv1.y, w1); fma4(acc[1], xv1.z, w2); fma4(acc[1], xv1.w, w3);
      fma4(acc[2], xv2.x, w0); fma4(acc[2], xv2.y, w1); fma4(acc[2], xv2.z, w2); fma4(acc[2], xv2.w, w3);
      fma4(acc[3], xv3.x, w0); fma4(acc[3], xv3.y, w1); fma4(acc[3], xv3.z, w2); fma4(acc[3], xv3.w, w3);
    }
#pragma unroll
    for (int i = 0; i < 4; ++i) {
      int gr = r0 + rb + i;
      if (gr < nrows) {
        float d = dis[gr];
        ushort4 o;
        o.x = f2bf(acc[i].x * d); o.y = f2bf(acc[i].y * d);
        o.z = f2bf(acc[i].z * d); o.w = f2bf(acc[i].w * d);
        ((ushort4*)S)[(size_t)gr * CQ + cq] = o;
      }
    }
  }
}

// h[i] = relu(dis[i]*(s[i] + sum_{j in nbr(i)} s[j]) + b), 128 bf16 cols in, fp32 out
__global__ __launch_bounds__(256) void k_agg1(const unsigned short* __restrict__ S,
                                              const int* __restrict__ rowptr,
                                              const int* __restrict__ csr,
                                              const float* __restrict__ dis,
                                              const float* __restrict__ b,
                                              float* __restrict__ H, int n) {
  int node = blockIdx.x * 4 + (threadIdx.x >> 6);
  if (node >= n) return;
  int lane = threadIdx.x & 63;              // covers cols 2*lane, 2*lane+1
  const ushort2* S2 = (const ushort2*)S;    // 64 ushort2 per 128-col row
  ushort2 sv = S2[(size_t)node * 64 + lane];
  float ax = bf2f(sv.x), ay = bf2f(sv.y);   // self-loop term
  int lo = rowptr[node], hi = rowptr[node + 1];
  int e = lo;
  for (; e + 3 < hi; e += 4) {
    int j0 = csr[e], j1 = csr[e + 1], j2 = csr[e + 2], j3 = csr[e + 3];
    ushort2 v0 = S2[(size_t)j0 * 64 + lane];
    ushort2 v1 = S2[(size_t)j1 * 64 + lane];
    ushort2 v2 = S2[(size_t)j2 * 64 + lane];
    ushort2 v3 = S2[(size_t)j3 * 64 + lane];
    ax += bf2f(v0.x) + bf2f(v1.x) + bf2f(v2.x) + bf2f(v3.x);
    ay += bf2f(v0.y) + bf2f(v1.y) + bf2f(v2.y) + bf2f(v3.y);
  }
  for (; e < hi; ++e) {
    ushort2 v = S2[(size_t)csr[e] * 64 + lane];
    ax += bf2f(v.x); ay += bf2f(v.y);
  }
  float d = dis[node];
  float2 bb = ((const float2*)b)[lane];
  float hx = fmaf(ax, d, bb.x);
  float hy = fmaf(ay, d, bb.y);
  ((float2*)H)[(size_t)node * 64 + lane] = make_float2(fmaxf(hx, 0.f), fmaxf(hy, 0.f));
}

// out[i] = dis[i]*(s[i] + sum nbr s[j]) + b, 64 bf16 cols in, fp32 out
__global__ __launch_bounds__(256) void k_agg2(const unsigned short* __restrict__ S,
                                              const int* __restrict__ rowptr,
                                              const int* __restrict__ csr,
                                              const float* __restrict__ dis,
                                              const float* __restrict__ b,
                                              float* __restrict__ O, int n) {
  int node = blockIdx.x * 4 + (threadIdx.x >> 6);
  if (node >= n) return;
  int lane = threadIdx.x & 63;
  float acc = bf2f(S[(size_t)node * 64 + lane]);
  int lo = rowptr[node], hi = rowptr[node + 1];
  int e = lo;
  for (; e + 3 < hi; e += 4) {
    int j0 = csr[e], j1 = csr[e + 1], j2 = csr[e + 2], j3 = csr[e + 3];
    float v0 = bf2f(S[(size_t)j0 * 64 + lane]);
    float v1 = bf2f(S[(size_t)j1 * 64 + lane]);
    float v2 = bf2f(S[(size_t)j2 * 64 + lane]);
    float v3 = bf2f(S[(size_t)j3 * 64 + lane]);
    acc += v0 + v1 + v2 + v3;
  }
  for (; e < hi; ++e) acc += bf2f(S[(size_t)csr[e] * 64 + lane]);
  O[(size_t)node * 64 + lane] = fmaf(acc, dis[node], b[lane]);
}

extern "C" void kernel_launch(void* const* d_in, const int* in_sizes, int n_in,
                              void* d_out, int out_size, void* d_ws, size_t ws_size,
                              hipStream_t stream) {
  const float* x  = (const float*)d_in[0];
  const void*  ei = d_in[1];
  const float* W1 = (const float*)d_in[2];
  const float* b1 = (const float*)d_in[3];
  const float* W2 = (const float*)d_in[4];
  const float* b2 = (const float*)d_in[5];
  float* out = (float*)d_out;

  const int N = in_sizes[0] / 128;   // 100000
  const int E = in_sizes[1] / 2;     // 1600000
  const int npb  = (N + NBKT - 1) / NBKT;    // 196 nodes per bucket
  const int nblk = (E + EPB - 1) / EPB;      // 196 partition blocks
  const int m    = NBKT * nblk;              // histogram entries

  char* w = (char*)d_ws;
  size_t off = 0;
  auto alloc = [&](size_t bytes) -> void* {
    void* p = (void*)(w + off);
    off += (bytes + 255) & ~(size_t)255;
    return p;
  };
  int*            deg     = (int*)alloc((size_t)N * 4);
  int*            rowptr  = (int*)alloc((size_t)(N + 1) * 4);
  int*            cursor  = (int*)alloc((size_t)N * 4);
  float*          dis     = (float*)alloc((size_t)N * 4);
  int*            csr     = (int*)alloc((size_t)E * 4);
  unsigned*       pairbuf = (unsigned*)alloc((size_t)E * 4);
  int*            hist    = (int*)alloc((size_t)m * 4);
  int*            scanned = (int*)alloc((size_t)m * 4);
  unsigned short* s       = (unsigned short*)alloc((size_t)N * 128 * 2);  // s1 bf16, then s2
  float*          h       = (float*)alloc((size_t)N * 128 * 4);
  int*            flag    = (int*)alloc(4);
  int*            partial = (int*)alloc(256 * 4);

  int gN = (N + 255) / 256;
  int gE = (E + 255) / 256;
  int npartsN = (N + SCAN_CHUNK - 1) / SCAN_CHUNK;  // 25
  int npartsM = (m + SCAN_CHUNK - 1) / SCAN_CHUNK;  // 25

  k_detect<<<1, 64, 0, stream>>>((const unsigned*)ei, flag);
  k_deg_init<<<gN, 256, 0, stream>>>(deg, N);
  k_deg_count<<<gE, 256, 0, stream>>>(ei, flag, deg, E);
  k_scan_part<<<npartsN, 256, 0, stream>>>(deg, partial, N);
  k_scan_top<<<1, 256, 0, stream>>>(partial, npartsN);
  k_scan_write<<<npartsN, 256, 0, stream>>>(deg, partial, rowptr, cursor, dis, N, E);

  k_hist<<<nblk, 256, 0, stream>>>(ei, flag, hist, E, nblk, npb);
  ks_part_g<<<npartsM, 256, 0, stream>>>(hist, partial, m);
  k_scan_top<<<1, 256, 0, stream>>>(partial, npartsM);
  ks_write_g<<<npartsM, 256, 0, stream>>>(hist, partial, scanned, m);
  k_partition<<<nblk, 256, 0, stream>>>(ei, flag, scanned, pairbuf, E, nblk, npb);
  k_bucket_csr<<<NBKT, 256, 0, stream>>>(pairbuf, rowptr, cursor, csr, N, npb);

  k_gemm<128><<<1024, 256, 0, stream>>>(x, W1, dis, s, N);
  k_agg1<<<(N + 3) / 4, 256, 0, stream>>>(s, rowptr, csr, dis, b1, h, N);
  k_gemm<64><<<1024, 256, 0, stream>>>(h, W2, dis, s, N);
  k_agg2<<<(N + 3) / 4, 256, 0, stream>>>(s, rowptr, csr, dis, b2, out, N);
}

// Round 5
// 320.942 us; speedup vs baseline: 2.1215x; 1.1938x over previous
//
#include <hip/hip_runtime.h>

// 2-layer GCN (PyG GCNConv): self-loops, symmetric deg-norm, bias.
// CSR build: deg -> scan -> bucket-histogram partition -> per-bucket LDS scatter.
// Compute: s1=bf16((x@W1)*dis) [MFMA] -> agg1(+b1,relu)->h bf16 ->
//          s2=bf16((h@W2)*dis) [MFMA] -> agg2(+b2)

constexpr int SCAN_CHUNK = 4096;
constexpr int NBKT = 512;
constexpr int EPB  = 8192;
constexpr int CSR_CAP = 12288;

using short8 = __attribute__((ext_vector_type(8))) short;
using f32x4  = __attribute__((ext_vector_type(4))) float;

__device__ __forceinline__ unsigned short f2bf(float f) {
  unsigned u = __float_as_uint(f);
  unsigned r = (u + 0x7FFFu + ((u >> 16) & 1u)) >> 16;   // RNE
  return (unsigned short)r;
}
__device__ __forceinline__ float bf2f(unsigned short h) {
  return __uint_as_float(((unsigned)h) << 16);
}

__global__ void k_detect(const unsigned* __restrict__ ei, int* __restrict__ flag) {
  if (threadIdx.x == 0 && blockIdx.x == 0) {
    int is64 = 1;
    for (int i = 1; i < 256; i += 2)
      if (ei[i] != 0u) { is64 = 0; break; }
    *flag = is64;
  }
}

__global__ void k_deg_init(int* __restrict__ deg, int n) {
  int i = blockIdx.x * blockDim.x + threadIdx.x;
  if (i < n) deg[i] = 1;
}

__device__ __forceinline__ int ld_idx(const void* ei, int is64, long long i) {
  return is64 ? (int)((const long long*)ei)[i] : ((const int*)ei)[i];
}

__global__ void k_deg_count(const void* __restrict__ ei, const int* __restrict__ flag,
                            int* __restrict__ deg, int e) {
  int i = blockIdx.x * blockDim.x + threadIdx.x;
  if (i >= e) return;
  int is64 = *flag;
  int d = ld_idx(ei, is64, (long long)e + i);
  atomicAdd(&deg[d], 1);
}

__global__ __launch_bounds__(256) void k_scan_part(const int* __restrict__ deg,
                                                   int* __restrict__ partial, int n) {
  __shared__ int red[256];
  int b = blockIdx.x, tid = threadIdx.x;
  int base = b * SCAN_CHUNK + tid * 16;
  int s = 0;
#pragma unroll
  for (int i = 0; i < 16; ++i) {
    int idx = base + i;
    if (idx < n) s += deg[idx] - 1;
  }
  red[tid] = s;
  __syncthreads();
  for (int off = 128; off > 0; off >>= 1) {
    if (tid < off) red[tid] += red[tid + off];
    __syncthreads();
  }
  if (tid == 0) partial[b] = red[0];
}

__global__ __launch_bounds__(256) void k_scan_top(int* __restrict__ partial, int nparts) {
  __shared__ int sums[256];
  int tid = threadIdx.x;
  sums[tid] = (tid < nparts) ? partial[tid] : 0;
  __syncthreads();
  for (int off = 1; off < 256; off <<= 1) {
    int t = (tid >= off) ? sums[tid - off] : 0;
    __syncthreads();
    sums[tid] += t;
    __syncthreads();
  }
  if (tid < nparts) partial[tid] = (tid == 0) ? 0 : sums[tid - 1];
}

__global__ __launch_bounds__(256) void k_scan_write(const int* __restrict__ deg,
                                                    const int* __restrict__ partial,
                                                    int* __restrict__ rowptr,
                                                    int* __restrict__ cursor,
                                                    float* __restrict__ dis,
                                                    int n, int e) {
  __shared__ int tsum[256];
  int b = blockIdx.x, tid = threadIdx.x;
  int base = b * SCAN_CHUNK + tid * 16;
  int vals[16];
  int dg[16];
  int s = 0;
#pragma unroll
  for (int i = 0; i < 16; ++i) {
    int idx = base + i;
    dg[i] = (idx < n) ? deg[idx] : 1;
    vals[i] = s;
    s += dg[i] - 1;
  }
  tsum[tid] = s;
  __syncthreads();
  for (int off = 1; off < 256; off <<= 1) {
    int t = (tid >= off) ? tsum[tid - off] : 0;
    __syncthreads();
    tsum[tid] += t;
    __syncthreads();
  }
  int toff = partial[b] + ((tid == 0) ? 0 : tsum[tid - 1]);
#pragma unroll
  for (int i = 0; i < 16; ++i) {
    int idx = base + i;
    if (idx < n) {
      int rp = toff + vals[i];
      rowptr[idx] = rp;
      cursor[idx] = rp;
      dis[idx] = rsqrtf((float)dg[i]);
    }
  }
  if (b == 0 && tid == 0) rowptr[n] = e;
}

__global__ __launch_bounds__(256) void ks_part_g(const int* __restrict__ in,
                                                 int* __restrict__ partial, int m) {
  __shared__ int red[256];
  int b = blockIdx.x, tid = threadIdx.x;
  int base = b * SCAN_CHUNK + tid * 16;
  int s = 0;
#pragma unroll
  for (int i = 0; i < 16; ++i) {
    int idx = base + i;
    if (idx < m) s += in[idx];
  }
  red[tid] = s;
  __syncthreads();
  for (int off = 128; off > 0; off >>= 1) {
    if (tid < off) red[tid] += red[tid + off];
    __syncthreads();
  }
  if (tid == 0) partial[b] = red[0];
}

__global__ __launch_bounds__(256) void ks_write_g(const int* __restrict__ in,
                                                  const int* __restrict__ partial,
                                                  int* __restrict__ out, int m) {
  __shared__ int tsum[256];
  int b = blockIdx.x, tid = threadIdx.x;
  int base = b * SCAN_CHUNK + tid * 16;
  int vals[16];
  int s = 0;
#pragma unroll
  for (int i = 0; i < 16; ++i) {
    int idx = base + i;
    int v = (idx < m) ? in[idx] : 0;
    vals[i] = s;
    s += v;
  }
  tsum[tid] = s;
  __syncthreads();
  for (int off = 1; off < 256; off <<= 1) {
    int t = (tid >= off) ? tsum[tid - off] : 0;
    __syncthreads();
    tsum[tid] += t;
    __syncthreads();
  }
  int toff = partial[b] + ((tid == 0) ? 0 : tsum[tid - 1]);
#pragma unroll
  for (int i = 0; i < 16; ++i) {
    int idx = base + i;
    if (idx < m) out[idx] = toff + vals[i];
  }
}

__global__ __launch_bounds__(256) void k_hist(const void* __restrict__ ei,
                                              const int* __restrict__ flag,
                                              int* __restrict__ hist,
                                              int e, int nblk, int npb) {
  __shared__ int h[NBKT];
  int blk = blockIdx.x, tid = threadIdx.x;
  for (int i = tid; i < NBKT; i += 256) h[i] = 0;
  __syncthreads();
  int is64 = *flag;
  int base = blk * EPB;
  int end = base + EPB; if (end > e) end = e;
  for (int i = base + tid; i < end; i += 256) {
    int d = ld_idx(ei, is64, (long long)e + i);
    atomicAdd(&h[d / npb], 1);
  }
  __syncthreads();
  for (int i = tid; i < NBKT; i += 256)
    hist[(size_t)i * nblk + blk] = h[i];
}

__global__ __launch_bounds__(256) void k_partition(const void* __restrict__ ei,
                                                   const int* __restrict__ flag,
                                                   const int* __restrict__ scanned,
                                                   unsigned* __restrict__ pairbuf,
                                                   int e, int nblk, int npb) {
  __shared__ int off[NBKT];
  int blk = blockIdx.x, tid = threadIdx.x;
  for (int i = tid; i < NBKT; i += 256)
    off[i] = scanned[(size_t)i * nblk + blk];
  __syncthreads();
  int is64 = *flag;
  int base = blk * EPB;
  int end = base + EPB; if (end > e) end = e;
  for (int i = base + tid; i < end; i += 256) {
    int s = ld_idx(ei, is64, i);
    int d = ld_idx(ei, is64, (long long)e + i);
    int bkt = d / npb;
    int pos = atomicAdd(&off[bkt], 1);
    pairbuf[pos] = (unsigned)s | ((unsigned)(d - bkt * npb) << 20);
  }
}

__global__ __launch_bounds__(256) void k_bucket_csr(const unsigned* __restrict__ pairbuf,
                                                    const int* __restrict__ rowptr,
                                                    int* __restrict__ cursor,
                                                    int* __restrict__ csr,
                                                    int n, int npb) {
  __shared__ int lcsr[CSR_CAP];
  __shared__ int cur[256];
  int b = blockIdx.x, tid = threadIdx.x;
  int lo = b * npb;
  if (lo >= n) return;
  int hi = lo + npb; if (hi > n) hi = n;
  int nn = hi - lo;
  int seg_base = rowptr[lo];
  int cnt = rowptr[hi] - seg_base;
  if (cnt <= CSR_CAP) {
    for (int i = tid; i < nn; i += 256) cur[i] = rowptr[lo + i] - seg_base;
    __syncthreads();
    for (int i = tid; i < cnt; i += 256) {
      unsigned p = pairbuf[seg_base + i];
      int q = atomicAdd(&cur[p >> 20], 1);
      lcsr[q] = (int)(p & 0xFFFFFu);
    }
    __syncthreads();
    for (int i = tid; i < cnt; i += 256) csr[seg_base + i] = lcsr[i];
  } else {
    for (int i = tid; i < cnt; i += 256) {
      unsigned p = pairbuf[seg_base + i];
      int d = lo + (int)(p >> 20);
      int q = atomicAdd(&cursor[d], 1);
      csr[q] = (int)(p & 0xFFFFFu);
    }
  }
}

// ---- MFMA bf16 GEMM: S[r][c] = bf16( dis[r] * sum_k X[r][k]*W[k][c] ), K=128 ----
// LDS tiles swizzled: ushort idx ^= (row&7)<<3  (== byte ^ (row&7)<<4) to kill
// the [rows][128]-bf16 stride-256B b128-read bank conflict (G4 recipe).
template <int NCOL, bool XBF16>
__global__ __launch_bounds__(256) void k_gemm_mfma(const void* __restrict__ Xv,
                                                   const float* __restrict__ W,
                                                   const float* __restrict__ dis,
                                                   unsigned short* __restrict__ S,
                                                   int nrows) {
  constexpr int ROWS = 64;
  constexpr int NCF = NCOL / 16;           // col-fragments per wave
  __shared__ __align__(16) unsigned short xs[ROWS * 128];
  __shared__ __align__(16) unsigned short wt[NCOL * 128];
  int tid = threadIdx.x;

  // stage W^T as bf16: wt[c][k] = W[k][c]   (coalesced global read)
  for (int id = tid; id < 128 * NCOL; id += 256) {
    int k = id / NCOL, c = id % NCOL;
    wt[(c * 128 + k) ^ ((c & 7) << 3)] = f2bf(W[id]);
  }

  int wv = tid >> 6, lane = tid & 63;
  int l16 = lane & 15, lk = lane >> 4;     // frag row/col + k-subgroup
  int arow = wv * 16 + l16;                // A row in tile (per lane)
  int npass = (nrows + ROWS - 1) / ROWS;

  for (int p = blockIdx.x; p < npass; p += gridDim.x) {
    int r0 = p * ROWS;
    __syncthreads();   // xs reuse fence (also covers wt on first pass)
    // stage X rows as bf16, 8 elems (16B) per chunk
#pragma unroll
    for (int it = 0; it < 4; ++it) {
      int id = tid + 256 * it;             // 1024 chunks
      int row = id >> 4, kc = id & 15;
      int gr = r0 + row;
      unsigned short v[8];
      if (gr < nrows) {
        if (XBF16) {
          const unsigned short* xb = (const unsigned short*)Xv + (size_t)gr * 128 + kc * 8;
#pragma unroll
          for (int j = 0; j < 8; ++j) v[j] = xb[j];
        } else {
          const float4* x4 = (const float4*)Xv + (size_t)gr * 32 + kc * 2;
          float4 f0 = x4[0], f1 = x4[1];
          v[0] = f2bf(f0.x); v[1] = f2bf(f0.y); v[2] = f2bf(f0.z); v[3] = f2bf(f0.w);
          v[4] = f2bf(f1.x); v[5] = f2bf(f1.y); v[6] = f2bf(f1.z); v[7] = f2bf(f1.w);
        }
      } else {
#pragma unroll
        for (int j = 0; j < 8; ++j) v[j] = 0;
      }
      int idx = (row * 128 + kc * 8) ^ ((row & 7) << 3);
      *(short8*)&xs[idx] = *(short8*)v;
    }
    __syncthreads();

    // A fragments: row = arow, k = ks*32 + lk*8 + 0..7
    short8 a[4];
#pragma unroll
    for (int ks = 0; ks < 4; ++ks)
      a[ks] = *(short8*)&xs[(arow * 128 + ks * 32 + lk * 8) ^ ((arow & 7) << 3)];

    f32x4 acc[NCF];
#pragma unroll
    for (int cf = 0; cf < NCF; ++cf) acc[cf] = (f32x4){0.f, 0.f, 0.f, 0.f};

#pragma unroll
    for (int cf = 0; cf < NCF; ++cf) {
      int col = cf * 16 + l16;
#pragma unroll
      for (int ks = 0; ks < 4; ++ks) {
        short8 b = *(short8*)&wt[(col * 128 + ks * 32 + lk * 8) ^ ((col & 7) << 3)];
        acc[cf] = __builtin_amdgcn_mfma_f32_16x16x32_bf16(a[ks], b, acc[cf], 0, 0, 0);
      }
    }

    // C/D: col = lane&15, row = (lane>>4)*4 + reg
#pragma unroll
    for (int r = 0; r < 4; ++r) {
      int gr = r0 + wv * 16 + lk * 4 + r;
      if (gr < nrows) {
        float dv = dis[gr];
#pragma unroll
        for (int cf = 0; cf < NCF; ++cf)
          S[(size_t)gr * NCOL + cf * 16 + l16] = f2bf(acc[cf][r] * dv);
      }
    }
  }
}

// h[i] = bf16(relu(dis[i]*(s[i] + sum nbr s[j]) + b)), 128 bf16 cols
__global__ __launch_bounds__(256) void k_agg1(const unsigned short* __restrict__ S,
                                              const int* __restrict__ rowptr,
                                              const int* __restrict__ csr,
                                              const float* __restrict__ dis,
                                              const float* __restrict__ b,
                                              unsigned short* __restrict__ H, int n) {
  int node = blockIdx.x * 4 + (threadIdx.x >> 6);
  if (node >= n) return;
  int lane = threadIdx.x & 63;
  const ushort2* S2 = (const ushort2*)S;
  ushort2 sv = S2[(size_t)node * 64 + lane];
  float ax = bf2f(sv.x), ay = bf2f(sv.y);
  int lo = rowptr[node], hi = rowptr[node + 1];
  int e = lo;
  for (; e + 3 < hi; e += 4) {
    int j0 = csr[e], j1 = csr[e + 1], j2 = csr[e + 2], j3 = csr[e + 3];
    ushort2 v0 = S2[(size_t)j0 * 64 + lane];
    ushort2 v1 = S2[(size_t)j1 * 64 + lane];
    ushort2 v2 = S2[(size_t)j2 * 64 + lane];
    ushort2 v3 = S2[(size_t)j3 * 64 + lane];
    ax += bf2f(v0.x) + bf2f(v1.x) + bf2f(v2.x) + bf2f(v3.x);
    ay += bf2f(v0.y) + bf2f(v1.y) + bf2f(v2.y) + bf2f(v3.y);
  }
  for (; e < hi; ++e) {
    ushort2 v = S2[(size_t)csr[e] * 64 + lane];
    ax += bf2f(v.x); ay += bf2f(v.y);
  }
  float d = dis[node];
  float2 bb = ((const float2*)b)[lane];
  float hx = fmaxf(fmaf(ax, d, bb.x), 0.f);
  float hy = fmaxf(fmaf(ay, d, bb.y), 0.f);
  ushort2 o; o.x = f2bf(hx); o.y = f2bf(hy);
  ((ushort2*)H)[(size_t)node * 64 + lane] = o;
}

// out[i] = dis[i]*(s[i] + sum nbr s[j]) + b, 64 bf16 cols in, fp32 out
__global__ __launch_bounds__(256) void k_agg2(const unsigned short* __restrict__ S,
                                              const int* __restrict__ rowptr,
                                              const int* __restrict__ csr,
                                              const float* __restrict__ dis,
                                              const float* __restrict__ b,
                                              float* __restrict__ O, int n) {
  int node = blockIdx.x * 4 + (threadIdx.x >> 6);
  if (node >= n) return;
  int lane = threadIdx.x & 63;
  float acc = bf2f(S[(size_t)node * 64 + lane]);
  int lo = rowptr[node], hi = rowptr[node + 1];
  int e = lo;
  for (; e + 3 < hi; e += 4) {
    int j0 = csr[e], j1 = csr[e + 1], j2 = csr[e + 2], j3 = csr[e + 3];
    float v0 = bf2f(S[(size_t)j0 * 64 + lane]);
    float v1 = bf2f(S[(size_t)j1 * 64 + lane]);
    float v2 = bf2f(S[(size_t)j2 * 64 + lane]);
    float v3 = bf2f(S[(size_t)j3 * 64 + lane]);
    acc += v0 + v1 + v2 + v3;
  }
  for (; e < hi; ++e) acc += bf2f(S[(size_t)csr[e] * 64 + lane]);
  O[(size_t)node * 64 + lane] = fmaf(acc, dis[node], b[lane]);
}

extern "C" void kernel_launch(void* const* d_in, const int* in_sizes, int n_in,
                              void* d_out, int out_size, void* d_ws, size_t ws_size,
                              hipStream_t stream) {
  const float* x  = (const float*)d_in[0];
  const void*  ei = d_in[1];
  const float* W1 = (const float*)d_in[2];
  const float* b1 = (const float*)d_in[3];
  const float* W2 = (const float*)d_in[4];
  const float* b2 = (const float*)d_in[5];
  float* out = (float*)d_out;

  const int N = in_sizes[0] / 128;
  const int E = in_sizes[1] / 2;
  const int npb  = (N + NBKT - 1) / NBKT;
  const int nblk = (E + EPB - 1) / EPB;
  const int m    = NBKT * nblk;

  char* w = (char*)d_ws;
  size_t off = 0;
  auto alloc = [&](size_t bytes) -> void* {
    void* p = (void*)(w + off);
    off += (bytes + 255) & ~(size_t)255;
    return p;
  };
  int*            deg     = (int*)alloc((size_t)N * 4);
  int*            rowptr  = (int*)alloc((size_t)(N + 1) * 4);
  int*            cursor  = (int*)alloc((size_t)N * 4);
  float*          dis     = (float*)alloc((size_t)N * 4);
  int*            csr     = (int*)alloc((size_t)E * 4);
  unsigned*       pairbuf = (unsigned*)alloc((size_t)E * 4);
  int*            hist    = (int*)alloc((size_t)m * 4);
  int*            scanned = (int*)alloc((size_t)m * 4);
  unsigned short* s       = (unsigned short*)alloc((size_t)N * 128 * 2);
  unsigned short* h       = (unsigned short*)alloc((size_t)N * 128 * 2);
  int*            flag    = (int*)alloc(4);
  int*            partial = (int*)alloc(256 * 4);

  int gN = (N + 255) / 256;
  int gE = (E + 255) / 256;
  int npartsN = (N + SCAN_CHUNK - 1) / SCAN_CHUNK;
  int npartsM = (m + SCAN_CHUNK - 1) / SCAN_CHUNK;

  k_detect<<<1, 64, 0, stream>>>((const unsigned*)ei, flag);
  k_deg_init<<<gN, 256, 0, stream>>>(deg, N);
  k_deg_count<<<gE, 256, 0, stream>>>(ei, flag, deg, E);
  k_scan_part<<<npartsN, 256, 0, stream>>>(deg, partial, N);
  k_scan_top<<<1, 256, 0, stream>>>(partial, npartsN);
  k_scan_write<<<npartsN, 256, 0, stream>>>(deg, partial, rowptr, cursor, dis, N, E);

  k_hist<<<nblk, 256, 0, stream>>>(ei, flag, hist, E, nblk, npb);
  ks_part_g<<<npartsM, 256, 0, stream>>>(hist, partial, m);
  k_scan_top<<<1, 256, 0, stream>>>(partial, npartsM);
  ks_write_g<<<npartsM, 256, 0, stream>>>(hist, partial, scanned, m);
  k_partition<<<nblk, 256, 0, stream>>>(ei, flag, scanned, pairbuf, E, nblk, npb);
  k_bucket_csr<<<NBKT, 256, 0, stream>>>(pairbuf, rowptr, cursor, csr, N, npb);

  k_gemm_mfma<128, false><<<1024, 256, 0, stream>>>(x, W1, dis, s, N);
  k_agg1<<<(N + 3) / 4, 256, 0, stream>>>(s, rowptr, csr, dis, b1, h, N);
  k_gemm_mfma<64, true><<<1024, 256, 0, stream>>>(h, W2, dis, s, N);
  k_agg2<<<(N + 3) / 4, 256, 0, stream>>>(s, rowptr, csr, dis, b2, out, N);
}

// Round 7
// 240.750 us; speedup vs baseline: 2.8281x; 1.3331x over previous
//
#include <hip/hip_runtime.h>

// 2-layer GCN (PyG GCNConv): self-loops, symmetric deg-norm, bias.
// CSR build (no global atomics): dst-bucket hist -> scan -> partition ->
//   per-bucket LDS {deg count, scan, rowptr/dis write, CSR scatter}.
// Compute: s1=bf16((x@W1)*dis) [MFMA] -> agg1(+b1,relu)->h bf16 ->
//          s2=bf16((h@W2)*dis) [MFMA] -> agg2(+b2)

constexpr int SCAN_CHUNK = 4096;
constexpr int NBKT = 512;          // dst buckets; npb = ceil(N/512) = 196 <= 256
constexpr int EPB  = 8192;         // edges per partition block
constexpr int CSR_CAP = 12288;     // per-bucket LDS CSR capacity (mean ~3130)

using short8 = __attribute__((ext_vector_type(8))) short;
using f32x4  = __attribute__((ext_vector_type(4))) float;

__device__ __forceinline__ unsigned short f2bf(float f) {
  unsigned u = __float_as_uint(f);
  unsigned r = (u + 0x7FFFu + ((u >> 16) & 1u)) >> 16;   // RNE
  return (unsigned short)r;
}
__device__ __forceinline__ float bf2f(unsigned short h) {
  return __uint_as_float(((unsigned)h) << 16);
}

__global__ void k_detect(const unsigned* __restrict__ ei, int* __restrict__ flag) {
  if (threadIdx.x == 0 && blockIdx.x == 0) {
    int is64 = 1;
    for (int i = 1; i < 256; i += 2)
      if (ei[i] != 0u) { is64 = 0; break; }
    *flag = is64;
  }
}

__device__ __forceinline__ int ld_idx(const void* ei, int is64, long long i) {
  return is64 ? (int)((const long long*)ei)[i] : ((const int*)ei)[i];
}

// ---- generic hierarchical exclusive scan (bucket histogram) ----

__global__ __launch_bounds__(256) void ks_part_g(const int* __restrict__ in,
                                                 int* __restrict__ partial, int m) {
  __shared__ int red[256];
  int b = blockIdx.x, tid = threadIdx.x;
  int base = b * SCAN_CHUNK + tid * 16;
  int s = 0;
#pragma unroll
  for (int i = 0; i < 16; ++i) {
    int idx = base + i;
    if (idx < m) s += in[idx];
  }
  red[tid] = s;
  __syncthreads();
  for (int off = 128; off > 0; off >>= 1) {
    if (tid < off) red[tid] += red[tid + off];
    __syncthreads();
  }
  if (tid == 0) partial[b] = red[0];
}

__global__ __launch_bounds__(256) void k_scan_top(int* __restrict__ partial, int nparts) {
  __shared__ int sums[256];
  int tid = threadIdx.x;
  sums[tid] = (tid < nparts) ? partial[tid] : 0;
  __syncthreads();
  for (int off = 1; off < 256; off <<= 1) {
    int t = (tid >= off) ? sums[tid - off] : 0;
    __syncthreads();
    sums[tid] += t;
    __syncthreads();
  }
  if (tid < nparts) partial[tid] = (tid == 0) ? 0 : sums[tid - 1];
}

__global__ __launch_bounds__(256) void ks_write_g(const int* __restrict__ in,
                                                  const int* __restrict__ partial,
                                                  int* __restrict__ out, int m) {
  __shared__ int tsum[256];
  int b = blockIdx.x, tid = threadIdx.x;
  int base = b * SCAN_CHUNK + tid * 16;
  int vals[16];
  int s = 0;
#pragma unroll
  for (int i = 0; i < 16; ++i) {
    int idx = base + i;
    int v = (idx < m) ? in[idx] : 0;
    vals[i] = s;
    s += v;
  }
  tsum[tid] = s;
  __syncthreads();
  for (int off = 1; off < 256; off <<= 1) {
    int t = (tid >= off) ? tsum[tid - off] : 0;
    __syncthreads();
    tsum[tid] += t;
    __syncthreads();
  }
  int toff = partial[b] + ((tid == 0) ? 0 : tsum[tid - 1]);
#pragma unroll
  for (int i = 0; i < 16; ++i) {
    int idx = base + i;
    if (idx < m) out[idx] = toff + vals[i];
  }
}

// ---- bucketed partition: edges -> packed (src | dlocal<<20) grouped by bucket ----

__global__ __launch_bounds__(256) void k_hist(const void* __restrict__ ei,
                                              const int* __restrict__ flag,
                                              int* __restrict__ hist,
                                              int e, int nblk, int npb) {
  __shared__ int h[NBKT];
  int blk = blockIdx.x, tid = threadIdx.x;
  for (int i = tid; i < NBKT; i += 256) h[i] = 0;
  __syncthreads();
  int is64 = *flag;
  int base = blk * EPB;
  int end = base + EPB; if (end > e) end = e;
  for (int i = base + tid; i < end; i += 256) {
    int d = ld_idx(ei, is64, (long long)e + i);
    atomicAdd(&h[d / npb], 1);
  }
  __syncthreads();
  for (int i = tid; i < NBKT; i += 256)
    hist[(size_t)i * nblk + blk] = h[i];   // bucket-major
}

__global__ __launch_bounds__(256) void k_partition(const void* __restrict__ ei,
                                                   const int* __restrict__ flag,
                                                   const int* __restrict__ scanned,
                                                   unsigned* __restrict__ pairbuf,
                                                   int e, int nblk, int npb) {
  __shared__ int off[NBKT];
  int blk = blockIdx.x, tid = threadIdx.x;
  for (int i = tid; i < NBKT; i += 256)
    off[i] = scanned[(size_t)i * nblk + blk];
  __syncthreads();
  int is64 = *flag;
  int base = blk * EPB;
  int end = base + EPB; if (end > e) end = e;
  for (int i = base + tid; i < end; i += 256) {
    int s = ld_idx(ei, is64, i);
    int d = ld_idx(ei, is64, (long long)e + i);
    int bkt = d / npb;
    int pos = atomicAdd(&off[bkt], 1);
    pairbuf[pos] = (unsigned)s | ((unsigned)(d - bkt * npb) << 20);
  }
}

// one block per bucket: LDS deg-count -> LDS scan -> rowptr/cursor/dis write
// (coalesced) -> LDS CSR scatter -> coalesced CSR write. No global atomics.
__global__ __launch_bounds__(256) void k_bucket_all(const unsigned* __restrict__ pairbuf,
                                                    const int* __restrict__ scanned,
                                                    int* __restrict__ rowptr,
                                                    int* __restrict__ cursor,
                                                    float* __restrict__ dis,
                                                    int* __restrict__ csr,
                                                    int n, int e, int npb, int nblk) {
  __shared__ int lcsr[CSR_CAP];
  __shared__ int cnt[256];     // per-node count, later scatter cursor
  __shared__ int scn[256];     // inclusive scan
  int b = blockIdx.x, tid = threadIdx.x;
  // sentinel from a block that always runs (bucket NBKT-1 may early-return!)
  if (b == 0 && tid == 0) rowptr[n] = e;
  int lo = b * npb;
  if (lo >= n) return;
  int hi = lo + npb; if (hi > n) hi = n;
  int nn = hi - lo;
  int seg_base = scanned[(size_t)b * nblk];
  int seg_end  = (b == NBKT - 1) ? e : scanned[(size_t)(b + 1) * nblk];
  int cnt_total = seg_end - seg_base;

  for (int i = tid; i < nn; i += 256) cnt[i] = 0;
  __syncthreads();
  for (int i = tid; i < cnt_total; i += 256)
    atomicAdd(&cnt[pairbuf[seg_base + i] >> 20], 1);
  __syncthreads();

  int v = (tid < nn) ? cnt[tid] : 0;    // this node's edge count (excl self-loop)
  scn[tid] = v;
  __syncthreads();
  for (int off = 1; off < 256; off <<= 1) {
    int t = (tid >= off) ? scn[tid - off] : 0;
    __syncthreads();
    scn[tid] += t;
    __syncthreads();
  }
  int start = (tid == 0) ? 0 : scn[tid - 1];   // exclusive within bucket
  if (tid < nn) {
    int node = lo + tid;
    rowptr[node] = seg_base + start;
    cursor[node] = seg_base + start;           // fallback path only
    dis[node] = rsqrtf((float)(v + 1));        // deg incl. self-loop
  }
  __syncthreads();
  if (tid < nn) cnt[tid] = start;              // scatter cursors (bucket-local)
  __syncthreads();

  if (cnt_total <= CSR_CAP) {
    for (int i = tid; i < cnt_total; i += 256) {
      unsigned p = pairbuf[seg_base + i];
      int q = atomicAdd(&cnt[p >> 20], 1);
      lcsr[q] = (int)(p & 0xFFFFFu);
    }
    __syncthreads();
    for (int i = tid; i < cnt_total; i += 256) csr[seg_base + i] = lcsr[i];
  } else {
    // statistically-unreachable overflow fallback: global atomics
    for (int i = tid; i < cnt_total; i += 256) {
      unsigned p = pairbuf[seg_base + i];
      int q = atomicAdd(&cursor[lo + (int)(p >> 20)], 1);
      csr[q] = (int)(p & 0xFFFFFu);
    }
  }
}

// ---- MFMA bf16 GEMM: S[r][c] = bf16( dis[r] * sum_k X[r][k]*W[k][c] ), K=128 ----
template <int NCOL, bool XBF16>
__global__ __launch_bounds__(256) void k_gemm_mfma(const void* __restrict__ Xv,
                                                   const float* __restrict__ W,
                                                   const float* __restrict__ dis,
                                                   unsigned short* __restrict__ S,
                                                   int nrows) {
  constexpr int ROWS = 64;
  constexpr int NCF = NCOL / 16;
  __shared__ __align__(16) unsigned short xs[ROWS * 128];
  __shared__ __align__(16) unsigned short wt[NCOL * 128];
  int tid = threadIdx.x;

  for (int id = tid; id < 128 * NCOL; id += 256) {
    int k = id / NCOL, c = id % NCOL;
    wt[(c * 128 + k) ^ ((c & 7) << 3)] = f2bf(W[id]);
  }

  int wv = tid >> 6, lane = tid & 63;
  int l16 = lane & 15, lk = lane >> 4;
  int arow = wv * 16 + l16;
  int npass = (nrows + ROWS - 1) / ROWS;

  for (int p = blockIdx.x; p < npass; p += gridDim.x) {
    int r0 = p * ROWS;
    __syncthreads();
#pragma unroll
    for (int it = 0; it < 4; ++it) {
      int id = tid + 256 * it;
      int row = id >> 4, kc = id & 15;
      int gr = r0 + row;
      unsigned short v[8];
      if (gr < nrows) {
        if (XBF16) {
          const unsigned short* xb = (const unsigned short*)Xv + (size_t)gr * 128 + kc * 8;
#pragma unroll
          for (int j = 0; j < 8; ++j) v[j] = xb[j];
        } else {
          const float4* x4 = (const float4*)Xv + (size_t)gr * 32 + kc * 2;
          float4 f0 = x4[0], f1 = x4[1];
          v[0] = f2bf(f0.x); v[1] = f2bf(f0.y); v[2] = f2bf(f0.z); v[3] = f2bf(f0.w);
          v[4] = f2bf(f1.x); v[5] = f2bf(f1.y); v[6] = f2bf(f1.z); v[7] = f2bf(f1.w);
        }
      } else {
#pragma unroll
        for (int j = 0; j < 8; ++j) v[j] = 0;
      }
      int idx = (row * 128 + kc * 8) ^ ((row & 7) << 3);
      *(short8*)&xs[idx] = *(short8*)v;
    }
    __syncthreads();

    short8 a[4];
#pragma unroll
    for (int ks = 0; ks < 4; ++ks)
      a[ks] = *(short8*)&xs[(arow * 128 + ks * 32 + lk * 8) ^ ((arow & 7) << 3)];

    f32x4 acc[NCF];
#pragma unroll
    for (int cf = 0; cf < NCF; ++cf) acc[cf] = (f32x4){0.f, 0.f, 0.f, 0.f};

#pragma unroll
    for (int cf = 0; cf < NCF; ++cf) {
      int col = cf * 16 + l16;
#pragma unroll
      for (int ks = 0; ks < 4; ++ks) {
        short8 bfr = *(short8*)&wt[(col * 128 + ks * 32 + lk * 8) ^ ((col & 7) << 3)];
        acc[cf] = __builtin_amdgcn_mfma_f32_16x16x32_bf16(a[ks], bfr, acc[cf], 0, 0, 0);
      }
    }

#pragma unroll
    for (int r = 0; r < 4; ++r) {
      int gr = r0 + wv * 16 + lk * 4 + r;
      if (gr < nrows) {
        float dv = dis[gr];
#pragma unroll
        for (int cf = 0; cf < NCF; ++cf)
          S[(size_t)gr * NCOL + cf * 16 + l16] = f2bf(acc[cf][r] * dv);
      }
    }
  }
}

// h[i] = bf16(relu(dis[i]*(s[i] + sum nbr s[j]) + b)), 128 bf16 cols
__global__ __launch_bounds__(256) void k_agg1(const unsigned short* __restrict__ S,
                                              const int* __restrict__ rowptr,
                                              const int* __restrict__ csr,
                                              const float* __restrict__ dis,
                                              const float* __restrict__ b,
                                              unsigned short* __restrict__ H, int n) {
  int node = blockIdx.x * 4 + (threadIdx.x >> 6);
  if (node >= n) return;
  int lane = threadIdx.x & 63;
  const ushort2* S2 = (const ushort2*)S;
  ushort2 sv = S2[(size_t)node * 64 + lane];
  float ax = bf2f(sv.x), ay = bf2f(sv.y);
  int lo = rowptr[node], hi = rowptr[node + 1];
  int e = lo;
  for (; e + 3 < hi; e += 4) {
    int j0 = csr[e], j1 = csr[e + 1], j2 = csr[e + 2], j3 = csr[e + 3];
    ushort2 v0 = S2[(size_t)j0 * 64 + lane];
    ushort2 v1 = S2[(size_t)j1 * 64 + lane];
    ushort2 v2 = S2[(size_t)j2 * 64 + lane];
    ushort2 v3 = S2[(size_t)j3 * 64 + lane];
    ax += bf2f(v0.x) + bf2f(v1.x) + bf2f(v2.x) + bf2f(v3.x);
    ay += bf2f(v0.y) + bf2f(v1.y) + bf2f(v2.y) + bf2f(v3.y);
  }
  for (; e < hi; ++e) {
    ushort2 v = S2[(size_t)csr[e] * 64 + lane];
    ax += bf2f(v.x); ay += bf2f(v.y);
  }
  float d = dis[node];
  float2 bb = ((const float2*)b)[lane];
  float hx = fmaxf(fmaf(ax, d, bb.x), 0.f);
  float hy = fmaxf(fmaf(ay, d, bb.y), 0.f);
  ushort2 o; o.x = f2bf(hx); o.y = f2bf(hy);
  ((ushort2*)H)[(size_t)node * 64 + lane] = o;
}

// out[i] = dis[i]*(s[i] + sum nbr s[j]) + b, 64 bf16 cols in, fp32 out
__global__ __launch_bounds__(256) void k_agg2(const unsigned short* __restrict__ S,
                                              const int* __restrict__ rowptr,
                                              const int* __restrict__ csr,
                                              const float* __restrict__ dis,
                                              const float* __restrict__ b,
                                              float* __restrict__ O, int n) {
  int node = blockIdx.x * 4 + (threadIdx.x >> 6);
  if (node >= n) return;
  int lane = threadIdx.x & 63;
  float acc = bf2f(S[(size_t)node * 64 + lane]);
  int lo = rowptr[node], hi = rowptr[node + 1];
  int e = lo;
  for (; e + 3 < hi; e += 4) {
    int j0 = csr[e], j1 = csr[e + 1], j2 = csr[e + 2], j3 = csr[e + 3];
    float v0 = bf2f(S[(size_t)j0 * 64 + lane]);
    float v1 = bf2f(S[(size_t)j1 * 64 + lane]);
    float v2 = bf2f(S[(size_t)j2 * 64 + lane]);
    float v3 = bf2f(S[(size_t)j3 * 64 + lane]);
    acc += v0 + v1 + v2 + v3;
  }
  for (; e < hi; ++e) acc += bf2f(S[(size_t)csr[e] * 64 + lane]);
  O[(size_t)node * 64 + lane] = fmaf(acc, dis[node], b[lane]);
}

extern "C" void kernel_launch(void* const* d_in, const int* in_sizes, int n_in,
                              void* d_out, int out_size, void* d_ws, size_t ws_size,
                              hipStream_t stream) {
  const float* x  = (const float*)d_in[0];
  const void*  ei = d_in[1];
  const float* W1 = (const float*)d_in[2];
  const float* b1 = (const float*)d_in[3];
  const float* W2 = (const float*)d_in[4];
  const float* b2 = (const float*)d_in[5];
  float* out = (float*)d_out;

  const int N = in_sizes[0] / 128;
  const int E = in_sizes[1] / 2;
  const int npb  = (N + NBKT - 1) / NBKT;    // 196
  const int nblk = (E + EPB - 1) / EPB;      // 196
  const int m    = NBKT * nblk;

  char* w = (char*)d_ws;
  size_t off = 0;
  auto alloc = [&](size_t bytes) -> void* {
    void* p = (void*)(w + off);
    off += (bytes + 255) & ~(size_t)255;
    return p;
  };
  int*            rowptr  = (int*)alloc((size_t)(N + 1) * 4);
  int*            cursor  = (int*)alloc((size_t)N * 4);
  float*          dis     = (float*)alloc((size_t)N * 4);
  int*            csr     = (int*)alloc((size_t)E * 4);
  unsigned*       pairbuf = (unsigned*)alloc((size_t)E * 4);
  int*            hist    = (int*)alloc((size_t)m * 4);
  int*            scanned = (int*)alloc((size_t)m * 4);
  unsigned short* s       = (unsigned short*)alloc((size_t)N * 128 * 2);
  unsigned short* h       = (unsigned short*)alloc((size_t)N * 128 * 2);
  int*            flag    = (int*)alloc(4);
  int*            partial = (int*)alloc(256 * 4);

  int npartsM = (m + SCAN_CHUNK - 1) / SCAN_CHUNK;

  k_detect<<<1, 64, 0, stream>>>((const unsigned*)ei, flag);
  k_hist<<<nblk, 256, 0, stream>>>(ei, flag, hist, E, nblk, npb);
  ks_part_g<<<npartsM, 256, 0, stream>>>(hist, partial, m);
  k_scan_top<<<1, 256, 0, stream>>>(partial, npartsM);
  ks_write_g<<<npartsM, 256, 0, stream>>>(hist, partial, scanned, m);
  k_partition<<<nblk, 256, 0, stream>>>(ei, flag, scanned, pairbuf, E, nblk, npb);
  k_bucket_all<<<NBKT, 256, 0, stream>>>(pairbuf, scanned, rowptr, cursor, dis, csr,
                                         N, E, npb, nblk);

  k_gemm_mfma<128, false><<<1024, 256, 0, stream>>>(x, W1, dis, s, N);
  k_agg1<<<(N + 3) / 4, 256, 0, stream>>>(s, rowptr, csr, dis, b1, h, N);
  k_gemm_mfma<64, true><<<1024, 256, 0, stream>>>(h, W2, dis, s, N);
  k_agg2<<<(N + 3) / 4, 256, 0, stream>>>(s, rowptr, csr, dis, b2, out, N);
}